// Round 15
// baseline (236.199 us; speedup 1.0000x reference)
//
#include <hip/hip_runtime.h>
#include <math.h>

#define NN 10000
#define NE 80000
#define SFH 102  // smF bf16 stride (free 2-way banks)
#define SFB 98   // F flush bf16 stride
#define SSB 66   // S flush bf16 stride
#define STX 72   // bf16 GEMM tile row stride
#define NTRI 528
#define SAE 104  // edge embed A stride (bf16)
#define SAN 72   // node embed A stride (bf16)

typedef __attribute__((ext_vector_type(8))) __bf16 bf16x8;
typedef __attribute__((ext_vector_type(8))) short short8v;
typedef __attribute__((ext_vector_type(4))) float f32x4;
typedef __attribute__((ext_vector_type(4))) unsigned uint4v;

__device__ __forceinline__ ushort f2bf(float x) {
  union { float f; unsigned u; } v; v.f = x;
  unsigned r = v.u + 0x7FFFu + ((v.u >> 16) & 1u);
  return (ushort)(r >> 16);
}
__device__ __forceinline__ float bfu(ushort u) {
  union { unsigned x; float f; } v; v.x = (unsigned)u << 16;
  return v.f;
}
__device__ __forceinline__ void tri_ab(int k, int& a, int& b) {
  int aa = 0, rem = k;
  while (rem >= 32 - aa) { rem -= 32 - aa; ++aa; }
  a = aa; b = aa + rem;
}

// ---- scan / scatter (verified R2/R3) ----
__global__ __launch_bounds__(1024)
void sgnn_scan(const int* __restrict__ deg, int* __restrict__ cursor,
               int* __restrict__ start) {
  __shared__ int sm[1024];
  __shared__ int carry;
  const int t = threadIdx.x;
  if (t == 0) carry = 0;
  __syncthreads();
  for (int base = 0; base < NN; base += 1024) {
    const int i = base + t;
    const int v = (i < NN) ? deg[i] : 0;
    sm[t] = v;
    __syncthreads();
    #pragma unroll
    for (int d = 1; d < 1024; d <<= 1) {
      const int add = (t >= d) ? sm[t - d] : 0;
      __syncthreads();
      sm[t] += add;
      __syncthreads();
    }
    const int excl = carry + sm[t] - v;
    if (i < NN) { cursor[i] = excl; start[i] = excl; }
    __syncthreads();
    if (t == 1023) carry += sm[1023];
    __syncthreads();
  }
}

__global__ __launch_bounds__(256)
void sgnn_scatter(const int* __restrict__ eidx, int* __restrict__ cursor,
                  int* __restrict__ sorted) {
  const int e = blockIdx.x * 256 + threadIdx.x;
  if (e < NE) {
    const int p = atomicAdd(cursor + eidx[e], 1);
    sorted[p] = e;
  }
}

// ---- weight convert + fused histogram (verified R11) ----
__global__ __launch_bounds__(256)
void sgnn_wconv(const float* __restrict__ nW1, const float* __restrict__ nW2,
                const float* __restrict__ nW3, const float* __restrict__ sW1,
                const float* __restrict__ sW2, const float* __restrict__ sW3,
                const float* __restrict__ Wemb1, const float* __restrict__ Wemb2,
                const int* __restrict__ eidx, int* __restrict__ deg,
                ushort* __restrict__ wout, ushort* __restrict__ tab) {
  const int gid = blockIdx.x * 256 + threadIdx.x;
  if (gid < NE) atomicAdd(deg + eidx[gid], 1);
  if (gid >= 61 * 4096) {
    const int k = gid - 61 * 4096;
    if (k < NTRI) {
      int a, b; tri_ab(k, a, b);
      tab[k] = (ushort)(a | (b << 8) | ((a != b) ? 0x8000 : 0));
    }
    return;
  }
  const int tile = gid >> 12, idx = gid & 4095;
  const int c = idx >> 6, k = idx & 63;
  float v = 0.f;
  if (tile < 12) {
    const int T = tile;
    if (T < 8 || (T == 8 && k < 16)) {
      const int ktri = T * 64 + k;
      if (ktri < NTRI) {
        int a, b; tri_ab(ktri, a, b);
        v = nW1[(a * 32 + b) * 64 + c];
        if (a != b) v += nW1[(b * 32 + a) * 64 + c];
      }
    } else if (T == 8) { if (k < 20) v = nW1[(1216 + (k - 16)) * 64 + c]; }
    else if (T == 9)   v = nW1[(1024 + k) * 64 + c];
    else if (T == 10)  v = nW1[(1088 + k) * 64 + c];
    else               v = nW1[(1152 + k) * 64 + c];
  } else if (tile == 12) v = nW2[k * 64 + c];
  else if (tile < 30)    v = nW3[k * 1088 + (tile - 13) * 64 + c];
  else if (tile < 41) {
    const int T = tile - 30;
    if (T < 8 || (T == 8 && k < 16)) {
      const int ktri = T * 64 + k;
      if (ktri < NTRI) {
        int a, b; tri_ab(ktri, a, b);
        v = sW1[(a * 32 + b) * 64 + c];
        if (a != b) v += sW1[(b * 32 + a) * 64 + c];
      }
    } else if (T == 9) v = sW1[(1024 + k) * 64 + c];
    else if (T == 10)  v = sW1[(1088 + k) * 64 + c];
  } else if (tile == 41) v = sW2[k * 64 + c];
  else if (tile < 59)    v = sW3[k * 1088 + (tile - 42) * 64 + c];
  else if (tile == 59) {
    const int col = idx / 96, kk = idx % 96;
    v = (col < 32 && kk < 65) ? Wemb1[kk * 32 + col] : 0.f;
  } else {
    const int col = idx >> 6;
    v = (col < 32) ? Wemb2[k * 32 + col] : 0.f;
  }
  wout[gid] = f2bf(v);
}

#define WPRE_LOAD(srcbase) do { const ushort* _s = (srcbase);                    \
  wpre0 = *(const short8v*)&_s[(t >> 3) * 64 + (t & 7) * 8];                     \
  wpre1 = *(const short8v*)&_s[(32 + (t >> 3)) * 64 + (t & 7) * 8]; } while (0)

#define WPRE_STORE_TO(Wd) do { ushort* _d = (Wd);                                \
  *(short8v*)&_d[(t >> 3) * STX + (t & 7) * 8] = wpre0;                          \
  *(short8v*)&_d[(32 + (t >> 3)) * STX + (t & 7) * 8] = wpre1; } while (0)

#define MFMA_K64_B(Xb, Wb) do { const ushort* _x = (Xb); const ushort* _wl = (Wb);\
  _Pragma("unroll") for (int kb = 0; kb < 2; ++kb) {                             \
    const bf16x8 af_ = *(const bf16x8*)&_x[(w * 16 + ll) * STX + kb * 32 + lh * 8]; \
    acc[0] = __builtin_amdgcn_mfma_f32_16x16x32_bf16(af_,                        \
        *(const bf16x8*)&_wl[(     ll) * STX + kb * 32 + lh * 8], acc[0], 0, 0, 0); \
    acc[1] = __builtin_amdgcn_mfma_f32_16x16x32_bf16(af_,                        \
        *(const bf16x8*)&_wl[(16 + ll) * STX + kb * 32 + lh * 8], acc[1], 0, 0, 0); \
    acc[2] = __builtin_amdgcn_mfma_f32_16x16x32_bf16(af_,                        \
        *(const bf16x8*)&_wl[(32 + ll) * STX + kb * 32 + lh * 8], acc[2], 0, 0, 0); \
    acc[3] = __builtin_amdgcn_mfma_f32_16x16x32_bf16(af_,                        \
        *(const bf16x8*)&_wl[(48 + ll) * STX + kb * 32 + lh * 8], acc[3], 0, 0, 0); \
  } } while (0)

#define ZERO_ACC() do { _Pragma("unroll") for (int q = 0; q < 4; ++q)            \
    acc[q] = (f32x4){0.f, 0.f, 0.f, 0.f}; } while (0)

#define PACK_STORE16(dstp) do {                                                  \
  unsigned pk[8];                                                                \
  _Pragma("unroll") for (int q = 0; q < 8; ++q)                                  \
    pk[q] = (unsigned)f2bf(xv[2 * q]) | ((unsigned)f2bf(xv[2 * q + 1]) << 16);   \
  *(uint4v*)(dstp)       = (uint4v){pk[0], pk[1], pk[2], pk[3]};                 \
  *(uint4v*)((dstp) + 8) = (uint4v){pk[4], pk[5], pk[6], pk[7]};                 \
} while (0)

#define TRI16(kt) do {                                                           \
  int prev_a = -1; float fa0 = 0.f, fa1 = 0.f, fa2 = 0.f;                        \
  _Pragma("unroll") for (int m = 0; m < 16; ++m) {                               \
    const int tb = tabL[(kt) + m];                                               \
    const int a_ = tb & 31, b_ = (tb >> 8) & 31;                                 \
    if (a_ != prev_a) { fa0 = bfu(fr[a_]); fa1 = bfu(fr[32 + a_]);               \
                        fa2 = bfu(fr[64 + a_]); prev_a = a_; }                   \
    const float v = fmaf(fa0, bfu(fr[b_]),                                       \
        fmaf(fa1, bfu(fr[32 + b_]), fa2 * bfu(fr[64 + b_])));                    \
    const float wsel = (tb & 0x8000) ? 2.f : 1.f;                                \
    sumsq = fmaf(v * wsel, v, sumsq);                                            \
    xv[m] = v;                                                                   \
  } } while (0)

#define XV_LOAD16(p) do { const float* _p = (p);                                 \
  _Pragma("unroll") for (int q = 0; q < 4; ++q) {                                \
    const float4 v4 = *(const float4*)(_p + 4 * q);                              \
    xv[4 * q + 0] = v4.x; xv[4 * q + 1] = v4.y;                                  \
    xv[4 * q + 2] = v4.z; xv[4 * q + 3] = v4.w; } } while (0)

#define CONSUME_NT() do {                                                        \
  _Pragma("unroll") for (int r = 0; r < 4; ++r) {                                \
    const int row_ = w * 16 + lh * 4 + r;                                        \
    const unsigned u0 = *(const unsigned*)&smFh[row_ * SFH +      nt * 2];       \
    const unsigned u1 = *(const unsigned*)&smFh[row_ * SFH + 32 + nt * 2];       \
    const unsigned u2 = *(const unsigned*)&smFh[row_ * SFH + 64 + nt * 2];       \
    union { unsigned x; float f; } l0, h0, l1, h1, l2, h2;                       \
    l0.x = u0 << 16; h0.x = u0 & 0xffff0000u;                                    \
    l1.x = u1 << 16; h1.x = u1 & 0xffff0000u;                                    \
    l2.x = u2 << 16; h2.x = u2 & 0xffff0000u;                                    \
    _Pragma("unroll") for (int nc = 0; nc < 4; ++nc) {                           \
      const float cv = (acc[nc][r] + b3v[nc]) * ifnr[r];                         \
      const int p = nc & 1;                                                      \
      const float f0 = (nc < 2) ? l0.f : h0.f;                                   \
      const float f1 = (nc < 2) ? l1.f : h1.f;                                   \
      const float f2 = (nc < 2) ? l2.f : h2.f;                                   \
      fch[(r * 3 + 0) * 2 + p] = fmaf(f0, cv, fch[(r * 3 + 0) * 2 + p]);         \
      fch[(r * 3 + 1) * 2 + p] = fmaf(f1, cv, fch[(r * 3 + 1) * 2 + p]);         \
      fch[(r * 3 + 2) * 2 + p] = fmaf(f2, cv, fch[(r * 3 + 2) * 2 + p]);         \
    }                                                                            \
  } } while (0)

#define STAGE_FS() do {                                                          \
  _Pragma("unroll") for (int r = 0; r < 4; ++r) {                                \
    const int row_ = w * 16 + lh * 4 + r;                                        \
    _Pragma("unroll") for (int i = 0; i < 3; ++i) {                              \
      F[row_ * SFB + i * 32 + ll]      = f2bf(fch[(r * 3 + i) * 2 + 0]);         \
      F[row_ * SFB + i * 32 + ll + 16] = f2bf(fch[(r * 3 + i) * 2 + 1]);         \
    }                                                                            \
    _Pragma("unroll") for (int nc = 0; nc < 4; ++nc)                             \
      S[row_ * SSB + nc * 16 + ll] = f2bf(cs[nc * 4 + r]);                       \
  } } while (0)

// LDS carve (52512 B, double-buffered Xl/Wl):
//  0      smFh [64][102] 13056 / F [64][98] 12544 (flush)
//  13056  Xl0 9216 / S [64][66] 8448 (flush) / Aemb (embed)
//  22272  Xl1 9216
//  31488  Wl0 9216
//  40704  Wl1 9216 (ends 49920)
//  49920  red f32[256] / icntL(node) / flush meta
//  50944  tabL[528] (1056) / iFn
//  52000  es_s int[64] | 52256 e0s | 52384 e1s (ends 52512)
#define LDS_BYTES 52512

__global__ __launch_bounds__(256, 2)
void sgnn_edge(const float* __restrict__ f, const float* __restrict__ s,
               const float* __restrict__ edge_f, const float* __restrict__ edge_s,
               const float* __restrict__ b1, const float* __restrict__ b2,
               const float* __restrict__ b3,
               const ushort* __restrict__ wbf, const ushort* __restrict__ tab_g,
               const int* __restrict__ eidx, const int* __restrict__ sorted,
               const int* __restrict__ start_g, const int* __restrict__ deg_g,
               float* __restrict__ fc_sum, float* __restrict__ sc_sum) {
  __shared__ __align__(16) char sbuf[LDS_BYTES];
  ushort* smFh = (ushort*)sbuf;
  ushort* F    = (ushort*)sbuf;
  ushort* Xl0  = (ushort*)(sbuf + 13056);
  ushort* S    = (ushort*)(sbuf + 13056);
  ushort* Aemb = (ushort*)(sbuf + 13056);  // [96][SAE] ends 33024 (pre-W-staging)
  ushort* Xl1  = (ushort*)(sbuf + 22272);
  ushort* Wl0  = (ushort*)(sbuf + 31488);
  ushort* Wl1  = (ushort*)(sbuf + 40704);
  float*  red  = (float*)(sbuf + 49920);
  int*    snode = (int*)(sbuf + 49920);
  int*    srow0 = snode + 8;
  int*    srow1 = snode + 16;
  int*    sst   = snode + 24;
  int*    sdg   = snode + 32;
  ushort* tabL = (ushort*)(sbuf + 50944);
  float*  iFn  = (float*)(sbuf + 50944);
  int*    es_s = (int*)(sbuf + 52000);
  ushort* e0s  = (ushort*)(sbuf + 52256);
  ushort* e1s  = (ushort*)(sbuf + 52384);

  const int t = threadIdx.x, j = t & 63, w = t >> 6, eb = w * 16;
  const int lh = j >> 4, ll = j & 15;
  const int bid = blockIdx.x;
  const ushort* wembT = wbf + 59 * 4096;
  short8v wpre0, wpre1;

  if (t < 64) {
    const int e = sorted[bid * 64 + t];
    es_s[t] = e;
    e0s[t] = (ushort)eidx[e];
    e1s[t] = (ushort)eidx[NE + e];
  }
  for (int idx = t; idx < NTRI; idx += 256) tabL[idx] = tab_g[idx];
  __syncthreads();

  int str = 0, dgr = 0;
  if (j < 16) {
    const int n_ = e0s[eb + j];
    str = start_g[n_];
    dgr = deg_g[n_];
  }
  WPRE_LOAD(wbf + 0);   // W1 tile 0

  // ---- MFMA embed (verified R9-R13) ----
  #pragma unroll 1
  for (int h = 0; h < 2; ++h) {
    const int hb = h * 32;
    #pragma unroll 1
    for (int cc = t; cc < 576; cc += 256) {
      const int row = cc / 6, seg = cc - row * 6;
      const int lel = (row * 43) >> 7, il = row - lel * 3;
      const int k0 = seg * 16;
      float xv[16];
      if (seg < 4) {
        const int nd = (seg < 2) ? (int)e0s[hb + lel] : (int)e1s[hb + lel];
        XV_LOAD16(f + nd * 96 + il * 32 + (seg & 1) * 16);
      } else if (seg == 4) {
        xv[0] = edge_f[es_s[hb + lel] * 3 + il];
        #pragma unroll
        for (int m = 1; m < 16; ++m) xv[m] = 0.f;
      } else {
        #pragma unroll
        for (int m = 0; m < 16; ++m) xv[m] = 0.f;
      }
      PACK_STORE16(&Aemb[row * SAE + k0]);
    }
    __syncthreads();
    #pragma unroll 1
    for (int job = w * 3; job < w * 3 + 3; ++job) {
      const int mt = job >> 1, nt = job & 1;
      f32x4 ac = (f32x4){0.f, 0.f, 0.f, 0.f};
      #pragma unroll
      for (int kb = 0; kb < 3; ++kb) {
        const bf16x8 av = *(const bf16x8*)&Aemb[(mt * 16 + ll) * SAE + kb * 32 + lh * 8];
        const bf16x8 bv = *(const bf16x8*)&wembT[(nt * 16 + ll) * 96 + kb * 32 + lh * 8];
        ac = __builtin_amdgcn_mfma_f32_16x16x32_bf16(av, bv, ac, 0, 0, 0);
      }
      #pragma unroll
      for (int r = 0; r < 4; ++r) {
        const int rr = mt * 16 + lh * 4 + r;
        const int lel = (rr * 43) >> 7, il = rr - lel * 3;
        smFh[(hb + lel) * SFH + il * 32 + nt * 16 + ll] = f2bf(ac[r]);
      }
    }
    __syncthreads();
  }

  f32x4 acc[4];
  ZERO_ACC();
  float sumsq = 0.f;

  // X-staging dispatch for stage T into Xd
  #define XSTAGE_E(T, Xd) do { ushort* _xd = (Xd);                               \
    const ushort* fr = smFh + j * SFH;                                           \
    float xv[16];                                                                \
    if ((T) < 8) { TRI16((T) * 64 + w * 16); }                                   \
    else if ((T) == 8) {                                                         \
      if (w == 0) { TRI16(512); }                                                \
      else if (w == 1) {                                                         \
        const float4 v4 = *(const float4*)(edge_s + es_s[j] * 68 + 64);          \
        xv[0] = v4.x; xv[1] = v4.y; xv[2] = v4.z; xv[3] = v4.w;                  \
        _Pragma("unroll") for (int m = 4; m < 16; ++m) xv[m] = 0.f;              \
      } else { _Pragma("unroll") for (int m = 0; m < 16; ++m) xv[m] = 0.f; }     \
    }                                                                            \
    else if ((T) == 9)  { XV_LOAD16(s + e0s[j] * 64 + w * 16); }                 \
    else if ((T) == 10) { XV_LOAD16(s + e1s[j] * 64 + w * 16); }                 \
    else                { XV_LOAD16(edge_s + es_s[j] * 68 + w * 16); }           \
    PACK_STORE16(&_xd[j * STX + w * 16]);                                        \
  } while (0)

  // ---- GEMM1: 12 stages, double-buffered, ONE barrier per stage ----
  XSTAGE_E(0, Xl0);
  WPRE_STORE_TO(Wl0);                 // W0
  WPRE_LOAD(wbf + 1 * 4096);          // W1
  __syncthreads();
  #pragma unroll 1
  for (int T = 0; T < 12; ++T) {
    ushort* Xc = (T & 1) ? Xl1 : Xl0;
    ushort* Wc = (T & 1) ? Wl1 : Wl0;
    ushort* Xn = (T & 1) ? Xl0 : Xl1;
    ushort* Wn = (T & 1) ? Wl0 : Wl1;
    if (T < 11) {
      XSTAGE_E(T + 1, Xn);
      WPRE_STORE_TO(Wn);              // W(T+1)
      WPRE_LOAD(wbf + (T + 2) * 4096); // T=10 loads tile12 (W2)
    }
    MFMA_K64_B(Xc, Wc);
    __syncthreads();
  }

  // ---- h1 epilogue: h1 -> Xl0, W2 -> Wl0 ----
  red[w * 64 + j] = sumsq;
  #pragma unroll
  for (int nc = 0; nc < 4; ++nc) {
    const float bv = b1[nc * 16 + ll];
    #pragma unroll
    for (int r = 0; r < 4; ++r)
      Xl0[(w * 16 + lh * 4 + r) * STX + nc * 16 + ll] = f2bf(fmaxf(acc[nc][r] + bv, 0.f));
  }
  WPRE_STORE_TO(Wl0);                 // W2
  WPRE_LOAD(wbf + 13 * 4096);         // W3 tile 0
  ZERO_ACC();
  __syncthreads();
  if (t < 64) {
    const float ss = red[t] + red[64 + t] + red[128 + t] + red[192 + t];
    iFn[t] = 1.f / (sqrtf(ss) + 1.f);
  }

  // ---- GEMM2 on (Xl0, Wl0); h2 -> Xl0 (own rows); W3_0 -> Wl1 ----
  MFMA_K64_B(Xl0, Wl0);
  #pragma unroll
  for (int nc = 0; nc < 4; ++nc) {
    const float bv = b2[nc * 16 + ll];
    #pragma unroll
    for (int r = 0; r < 4; ++r)
      Xl0[(w * 16 + lh * 4 + r) * STX + nc * 16 + ll] = f2bf(fmaxf(acc[nc][r] + bv, 0.f));
  }
  WPRE_STORE_TO(Wl1);                 // W3 tile 13
  WPRE_LOAD(wbf + 14 * 4096);         // W3 tile 14
  __syncthreads();

  // ---- GEMM3: 17 tiles, double-buffered W, ONE barrier per tile ----
  float fch[24];
  #pragma unroll
  for (int q = 0; q < 24; ++q) fch[q] = 0.f;
  float cs[16];
  float ifnr[4];
  #pragma unroll
  for (int r = 0; r < 4; ++r) ifnr[r] = iFn[w * 16 + lh * 4 + r];

  #pragma unroll 1
  for (int nt = 0; nt < 17; ++nt) {
    ushort* Wc = (nt & 1) ? Wl0 : Wl1;    // nt=0 -> Wl1 (tile13)
    ushort* Wn = (nt & 1) ? Wl1 : Wl0;
    if (nt < 16) {
      WPRE_STORE_TO(Wn);              // tile 14+nt
      if (nt < 15) WPRE_LOAD(wbf + (15 + nt) * 4096);
    }
    float b3v[4];
    #pragma unroll
    for (int nc = 0; nc < 4; ++nc) b3v[nc] = b3[nt * 64 + nc * 16 + ll];
    ZERO_ACC();
    MFMA_K64_B(Xl0, Wc);
    if (nt < 16) {
      CONSUME_NT();
    } else {
      #pragma unroll
      for (int nc = 0; nc < 4; ++nc)
        #pragma unroll
        for (int r = 0; r < 4; ++r)
          cs[nc * 4 + r] = (acc[nc][r] + b3v[nc]) * ifnr[r];
    }
    __syncthreads();
  }

  // ---- stage F/S (bf16), then run-flush (verified R5/R10/R11) ----
  STAGE_FS();
  if (t < 8) snode[t] = -1;
  __syncthreads();

  {
    float r0 = 0.f, r1 = 0.f, rs = 0.f;
    int runlen = 0;
    const int gwb = bid * 64 + eb;
    #pragma unroll 1
    for (int m = 0; m < 16; ++m) {
      const int row = eb + m;
      r0 += bfu(F[row * SFB + j]);
      if (j < 32) r1 += bfu(F[row * SFB + 64 + j]);
      rs += bfu(S[row * SSB + j]);
      ++runlen;
      const int n = e0s[row];
      if (m == 15 || e0s[row + 1] != n) {
        const int st = __shfl(str, m);
        const int dg = __shfl(dgr, m);
        const int g1v = gwb + m, g0v = g1v - runlen + 1;
        if (g0v == st && runlen == dg) {
          fc_sum[n * 96 + j] = r0;
          if (j < 32) fc_sum[n * 96 + 64 + j] = r1;
          sc_sum[n * 64 + j] = rs;
        } else {
          const int slot = (g0v == gwb) ? 2 * w : 2 * w + 1;
          if (j == 0) {
            snode[slot] = n; srow0[slot] = row - runlen + 1; srow1[slot] = row;
            sst[slot] = st; sdg[slot] = dg;
          }
        }
        r0 = r1 = rs = 0.f; runlen = 0;
      }
    }
  }
  __syncthreads();

  if (t < 160) {
    const int ch = t;
    int prevn = -1;
    #pragma unroll 1
    for (int ss = 0; ss < 8; ++ss) {
      const int n = snode[ss];
      if (n < 0) continue;
      if (n != prevn) {
        float v = 0.f;
        #pragma unroll 1
        for (int k2 = ss; k2 < 8; ++k2) {
          if (snode[k2] == n) {
            #pragma unroll 1
            for (int row = srow0[k2]; row <= srow1[k2]; ++row)
              v += (ch < 96) ? bfu(F[row * SFB + ch]) : bfu(S[row * SSB + (ch - 96)]);
          } else if (k2 > ss && snode[k2] >= 0) break;
        }
        const bool cib = (sst[ss] >= bid * 64) && (sst[ss] + sdg[ss] <= bid * 64 + 64);
        float* dst = (ch < 96) ? (fc_sum + n * 96 + ch) : (sc_sum + n * 64 + (ch - 96));
        if (cib) *dst = v; else atomicAdd(dst, v);
      }
      prevn = n;
    }
  }
}

__global__ __launch_bounds__(256, 2)
void sgnn_node(const float* __restrict__ f, const float* __restrict__ s,
               const float* __restrict__ b1, const float* __restrict__ b2,
               const float* __restrict__ b3,
               const ushort* __restrict__ wbf, const ushort* __restrict__ tab_g,
               const float* __restrict__ fcm, const float* __restrict__ scm,
               const int* __restrict__ deg_g,
               float* __restrict__ of, float* __restrict__ os) {
  __shared__ __align__(16) char sbuf[LDS_BYTES];
  ushort* smFh = (ushort*)sbuf;
  ushort* F    = (ushort*)sbuf;
  ushort* Xl0  = (ushort*)(sbuf + 13056);
  ushort* S    = (ushort*)(sbuf + 13056);
  ushort* Aemb = (ushort*)(sbuf + 13056);  // [96][SAN] ends 26880
  ushort* Xl1  = (ushort*)(sbuf + 22272);
  ushort* Wl0  = (ushort*)(sbuf + 31488);
  ushort* Wl1  = (ushort*)(sbuf + 40704);
  float*  red  = (float*)(sbuf + 49920);
  float*  icntL = (float*)(sbuf + 49920);
  ushort* tabL = (ushort*)(sbuf + 50944);
  float*  iFn  = (float*)(sbuf + 50944);

  const int t = threadIdx.x, j = t & 63, w = t >> 6, eb = w * 16;
  const int lh = j >> 4, ll = j & 15;
  const int nbase = blockIdx.x * 64;
  const ushort* wembTn = wbf + 60 * 4096;
  short8v wpre0, wpre1;

  for (int idx = t; idx < NTRI; idx += 256) tabL[idx] = tab_g[idx];
  if (t < 64)
    icntL[t] = 1.f / fmaxf((float)deg_g[min(nbase + t, NN - 1)], 1.f);
  WPRE_LOAD(wbf + 30 * 4096);         // W1 tile 30
  __syncthreads();

  // ---- MFMA embed ----
  #pragma unroll 1
  for (int h = 0; h < 2; ++h) {
    const int hb = h * 32;
    #pragma unroll 1
    for (int cc = t; cc < 384; cc += 256) {
      const int row = cc >> 2, seg = cc & 3;
      const int lel = (row * 43) >> 7, il = row - lel * 3;
      const int nc = min(nbase + hb + lel, NN - 1);
      const int k0 = seg * 16;
      float xv[16];
      if (seg < 2) {
        XV_LOAD16(f + nc * 96 + il * 32 + seg * 16);
      } else {
        XV_LOAD16(fcm + nc * 96 + il * 32 + (seg - 2) * 16);
        const float ic = icntL[hb + lel];
        #pragma unroll
        for (int m = 0; m < 16; ++m) xv[m] *= ic;
      }
      PACK_STORE16(&Aemb[row * SAN + k0]);
    }
    __syncthreads();
    #pragma unroll 1
    for (int job = w * 3; job < w * 3 + 3; ++job) {
      const int mt = job >> 1, nt = job & 1;
      f32x4 ac = (f32x4){0.f, 0.f, 0.f, 0.f};
      #pragma unroll
      for (int kb = 0; kb < 2; ++kb) {
        const bf16x8 av = *(const bf16x8*)&Aemb[(mt * 16 + ll) * SAN + kb * 32 + lh * 8];
        const bf16x8 bv = *(const bf16x8*)&wembTn[(nt * 16 + ll) * 64 + kb * 32 + lh * 8];
        ac = __builtin_amdgcn_mfma_f32_16x16x32_bf16(av, bv, ac, 0, 0, 0);
      }
      #pragma unroll
      for (int r = 0; r < 4; ++r) {
        const int rr = mt * 16 + lh * 4 + r;
        const int lel = (rr * 43) >> 7, il = rr - lel * 3;
        smFh[(hb + lel) * SFH + il * 32 + nt * 16 + ll] = f2bf(ac[r]);
      }
    }
    __syncthreads();
  }

  f32x4 acc[4];
  ZERO_ACC();
  float sumsq = 0.f;

  #define XSTAGE_N(T, Xd) do { ushort* _xd = (Xd);                               \
    const ushort* fr = smFh + j * SFH;                                           \
    float xv[16];                                                                \
    if ((T) < 8) { TRI16((T) * 64 + w * 16); }                                   \
    else if ((T) == 8) {                                                         \
      if (w == 0) { TRI16(512); }                                                \
      else { _Pragma("unroll") for (int m = 0; m < 16; ++m) xv[m] = 0.f; }       \
    }                                                                            \
    else if ((T) == 9) { XV_LOAD16(s + min(nbase + j, NN - 1) * 64 + w * 16); }  \
    else {                                                                       \
      XV_LOAD16(scm + min(nbase + j, NN - 1) * 64 + w * 16);                     \
      const float ic = icntL[j];                                                 \
      _Pragma("unroll") for (int m = 0; m < 16; ++m) xv[m] *= ic;                \
    }                                                                            \
    PACK_STORE16(&_xd[j * STX + w * 16]);                                        \
  } while (0)

  // ---- GEMM1: 11 stages, double-buffered ----
  XSTAGE_N(0, Xl0);
  WPRE_STORE_TO(Wl0);                 // tile 30
  WPRE_LOAD(wbf + 31 * 4096);
  __syncthreads();
  #pragma unroll 1
  for (int T = 0; T < 11; ++T) {
    ushort* Xc = (T & 1) ? Xl1 : Xl0;
    ushort* Wc = (T & 1) ? Wl1 : Wl0;
    ushort* Xn = (T & 1) ? Xl0 : Xl1;
    ushort* Wn = (T & 1) ? Wl0 : Wl1;
    if (T < 10) {
      XSTAGE_N(T + 1, Xn);
      WPRE_STORE_TO(Wn);              // tile 31+T
      WPRE_LOAD(wbf + (32 + T) * 4096); // T=9 loads tile 41 (W2)
    }
    MFMA_K64_B(Xc, Wc);
    __syncthreads();
  }

  // ---- h1 epilogue (last MFMA T=10 read Xl0/Wl0; barrier passed) ----
  red[w * 64 + j] = sumsq;
  #pragma unroll
  for (int nc = 0; nc < 4; ++nc) {
    const float bv = b1[nc * 16 + ll];
    #pragma unroll
    for (int r = 0; r < 4; ++r)
      Xl0[(w * 16 + lh * 4 + r) * STX + nc * 16 + ll] = f2bf(fmaxf(acc[nc][r] + bv, 0.f));
  }
  WPRE_STORE_TO(Wl0);                 // W2 (tile 41)
  WPRE_LOAD(wbf + 42 * 4096);         // W3 tile 42
  ZERO_ACC();
  __syncthreads();
  if (t < 64) {
    const float ss = red[t] + red[64 + t] + red[128 + t] + red[192 + t];
    iFn[t] = 1.f / (sqrtf(ss) + 1.f);
  }

  MFMA_K64_B(Xl0, Wl0);               // GEMM2
  #pragma unroll
  for (int nc = 0; nc < 4; ++nc) {
    const float bv = b2[nc * 16 + ll];
    #pragma unroll
    for (int r = 0; r < 4; ++r)
      Xl0[(w * 16 + lh * 4 + r) * STX + nc * 16 + ll] = f2bf(fmaxf(acc[nc][r] + bv, 0.f));
  }
  WPRE_STORE_TO(Wl1);                 // W3 tile 42
  WPRE_LOAD(wbf + 43 * 4096);         // W3 tile 43
  __syncthreads();

  // ---- GEMM3 ----
  float fch[24];
  #pragma unroll
  for (int q = 0; q < 24; ++q) fch[q] = 0.f;
  float cs[16];
  float ifnr[4];
  #pragma unroll
  for (int r = 0; r < 4; ++r) ifnr[r] = iFn[w * 16 + lh * 4 + r];

  #pragma unroll 1
  for (int nt = 0; nt < 17; ++nt) {
    ushort* Wc = (nt & 1) ? Wl0 : Wl1;   // nt=0 -> Wl1 (tile42)
    ushort* Wn = (nt & 1) ? Wl1 : Wl0;
    if (nt < 16) {
      WPRE_STORE_TO(Wn);              // tile 43+nt
      if (nt < 15) WPRE_LOAD(wbf + (44 + nt) * 4096);
    }
    float b3v[4];
    #pragma unroll
    for (int nc = 0; nc < 4; ++nc) b3v[nc] = b3[nt * 64 + nc * 16 + ll];
    ZERO_ACC();
    MFMA_K64_B(Xl0, Wc);
    if (nt < 16) {
      CONSUME_NT();
    } else {
      #pragma unroll
      for (int nc = 0; nc < 4; ++nc)
        #pragma unroll
        for (int r = 0; r < 4; ++r)
          cs[nc * 4 + r] = (acc[nc][r] + b3v[nc]) * ifnr[r];
    }
    __syncthreads();
  }

  // ---- stage F/S + residual writes ----
  STAGE_FS();
  __syncthreads();

  #pragma unroll 1
  for (int m = 0; m < 16; ++m) {
    const int row = eb + m;
    const int n_m = nbase + row;
    if (n_m < NN) {
      of[n_m * 96 + j] = bfu(F[row * SFB + j]) + f[n_m * 96 + j];
      if (j < 32)
        of[n_m * 96 + 64 + j] = bfu(F[row * SFB + 64 + j]) + f[n_m * 96 + 64 + j];
      os[n_m * 64 + j] = bfu(S[row * SSB + j]) + s[n_m * 64 + j];
    }
  }
}

extern "C" void kernel_launch(void* const* d_in, const int* in_sizes, int n_in,
                              void* d_out, int out_size, void* d_ws, size_t ws_size,
                              hipStream_t stream) {
  const float* f      = (const float*)d_in[0];
  const float* s      = (const float*)d_in[1];
  const float* edge_f = (const float*)d_in[2];
  const float* edge_s = (const float*)d_in[3];
  const float* Wemb1  = (const float*)d_in[4];
  const float* nW1 = (const float*)d_in[5];
  const float* nb1 = (const float*)d_in[6];
  const float* nW2 = (const float*)d_in[7];
  const float* nb2 = (const float*)d_in[8];
  const float* nW3 = (const float*)d_in[9];
  const float* nb3 = (const float*)d_in[10];
  const float* Wemb2 = (const float*)d_in[11];
  const float* sW1 = (const float*)d_in[12];
  const float* sb1 = (const float*)d_in[13];
  const float* sW2 = (const float*)d_in[14];
  const float* sb2 = (const float*)d_in[15];
  const float* sW3 = (const float*)d_in[16];
  const float* sb3 = (const float*)d_in[17];
  const int* eidx  = (const int*)d_in[18];

  float* of = (float*)d_out;
  float* os = of + (size_t)NN * 96;

  int* deg    = (int*)d_ws;
  int* cursor = deg + NN;
  int* start  = cursor + NN;
  int* sorted = start + NN;
  ushort* wbf = (ushort*)(sorted + NE);
  ushort* tab = wbf + 61 * 4096;

  hipMemsetAsync(deg, 0, (size_t)NN * 4, stream);
  hipMemsetAsync(d_out, 0, (size_t)NN * 160 * 4, stream);

  hipLaunchKernelGGL(sgnn_wconv, dim3((61 * 4096 + NTRI + 255) / 256), dim3(256),
                     0, stream, nW1, nW2, nW3, sW1, sW2, sW3, Wemb1, Wemb2,
                     eidx, deg, wbf, tab);
  hipLaunchKernelGGL(sgnn_scan, dim3(1), dim3(1024), 0, stream, deg, cursor, start);
  hipLaunchKernelGGL(sgnn_scatter, dim3((NE + 255) / 256), dim3(256), 0, stream,
                     eidx, cursor, sorted);
  hipLaunchKernelGGL(sgnn_edge, dim3(NE / 64), dim3(256), 0, stream,
                     f, s, edge_f, edge_s, nb1, nb2, nb3,
                     wbf, tab, eidx, sorted, start, deg,
                     of /*fc_sum*/, os /*sc_sum*/);
  hipLaunchKernelGGL(sgnn_node, dim3((NN + 63) / 64), dim3(256), 0, stream,
                     f, s, sb1, sb2, sb3,
                     wbf, tab, of /*fc sums*/, os /*sc sums*/, deg, of, os);
}

// Round 16
// 202.258 us; speedup vs baseline: 1.1678x; 1.1678x over previous
//
#include <hip/hip_runtime.h>
#include <math.h>

#define NN 10000
#define NE 80000
#define SFH 102  // smF bf16 stride: 204B row = 51 dwords (odd) -> 2-way max (free)
#define SFB 98   // F flush bf16 stride
#define SSB 66   // S flush bf16 stride
#define STX 72   // bf16 GEMM tile row stride
#define NTRI 528 // 32*33/2 unique Gram entries
#define SAE 104  // edge embed A stride (bf16)
#define SAN 72   // node embed A stride (bf16)

typedef __attribute__((ext_vector_type(8))) __bf16 bf16x8;
typedef __attribute__((ext_vector_type(8))) short short8v;
typedef __attribute__((ext_vector_type(4))) float f32x4;
typedef __attribute__((ext_vector_type(4))) unsigned uint4v;

__device__ __forceinline__ ushort f2bf(float x) {
  union { float f; unsigned u; } v; v.f = x;
  unsigned r = v.u + 0x7FFFu + ((v.u >> 16) & 1u);
  return (ushort)(r >> 16);
}
__device__ __forceinline__ float bfu(ushort u) {
  union { unsigned x; float f; } v; v.x = (unsigned)u << 16;
  return v.f;
}
__device__ __forceinline__ void tri_ab(int k, int& a, int& b) {
  int aa = 0, rem = k;
  while (rem >= 32 - aa) { rem -= 32 - aa; ++aa; }
  a = aa; b = aa + rem;
}

// ---- single-pass register-blocked scan (R15): 10 elems/thread, one LDS scan ----
__global__ __launch_bounds__(1024)
void sgnn_scan(const int* __restrict__ deg, int* __restrict__ cursor,
               int* __restrict__ start) {
  __shared__ int sm[1024];
  const int t = threadIdx.x;
  const int i0 = t * 10;
  int v[10], pre = 0;
  #pragma unroll
  for (int q = 0; q < 10; ++q) {
    const int i = i0 + q;
    v[q] = (i < NN) ? deg[i] : 0;
    pre += v[q];
  }
  sm[t] = pre;                    // chunk total
  __syncthreads();
  int run = pre;
  #pragma unroll
  for (int d = 1; d < 1024; d <<= 1) {
    const int add = (t >= d) ? sm[t - d] : 0;
    __syncthreads();
    run += add;
    sm[t] = run;
    __syncthreads();
  }
  int excl = run - pre;           // exclusive base of this chunk
  #pragma unroll
  for (int q = 0; q < 10; ++q) {
    const int i = i0 + q;
    if (i < NN) { cursor[i] = excl; start[i] = excl; }
    excl += v[q];
  }
}

__global__ __launch_bounds__(256)
void sgnn_scatter(const int* __restrict__ eidx, int* __restrict__ cursor,
                  int* __restrict__ sorted) {
  const int e = blockIdx.x * 256 + threadIdx.x;
  if (e < NE) {
    const int p = atomicAdd(cursor + eidx[e], 1);
    sorted[p] = e;
  }
}

// ---- weight convert + fused histogram (verified R11) ----
__global__ __launch_bounds__(256)
void sgnn_wconv(const float* __restrict__ nW1, const float* __restrict__ nW2,
                const float* __restrict__ nW3, const float* __restrict__ sW1,
                const float* __restrict__ sW2, const float* __restrict__ sW3,
                const float* __restrict__ Wemb1, const float* __restrict__ Wemb2,
                const int* __restrict__ eidx, int* __restrict__ deg,
                ushort* __restrict__ wout, ushort* __restrict__ tab) {
  const int gid = blockIdx.x * 256 + threadIdx.x;
  if (gid < NE) atomicAdd(deg + eidx[gid], 1);   // fused hist
  if (gid >= 61 * 4096) {
    const int k = gid - 61 * 4096;
    if (k < NTRI) {
      int a, b; tri_ab(k, a, b);
      tab[k] = (ushort)(a | (b << 8) | ((a != b) ? 0x8000 : 0));
    }
    return;
  }
  const int tile = gid >> 12, idx = gid & 4095;
  const int c = idx >> 6, k = idx & 63;
  float v = 0.f;
  if (tile < 12) {
    const int T = tile;
    if (T < 8 || (T == 8 && k < 16)) {
      const int ktri = T * 64 + k;
      if (ktri < NTRI) {
        int a, b; tri_ab(ktri, a, b);
        v = nW1[(a * 32 + b) * 64 + c];
        if (a != b) v += nW1[(b * 32 + a) * 64 + c];
      }
    } else if (T == 8) { if (k < 20) v = nW1[(1216 + (k - 16)) * 64 + c]; }
    else if (T == 9)   v = nW1[(1024 + k) * 64 + c];
    else if (T == 10)  v = nW1[(1088 + k) * 64 + c];
    else               v = nW1[(1152 + k) * 64 + c];
  } else if (tile == 12) v = nW2[k * 64 + c];
  else if (tile < 30)    v = nW3[k * 1088 + (tile - 13) * 64 + c];
  else if (tile < 41) {
    const int T = tile - 30;
    if (T < 8 || (T == 8 && k < 16)) {
      const int ktri = T * 64 + k;
      if (ktri < NTRI) {
        int a, b; tri_ab(ktri, a, b);
        v = sW1[(a * 32 + b) * 64 + c];
        if (a != b) v += sW1[(b * 32 + a) * 64 + c];
      }
    } else if (T == 9) v = sW1[(1024 + k) * 64 + c];
    else if (T == 10)  v = sW1[(1088 + k) * 64 + c];
  } else if (tile == 41) v = sW2[k * 64 + c];
  else if (tile < 59)    v = sW3[k * 1088 + (tile - 42) * 64 + c];
  else if (tile == 59) {
    const int col = idx / 96, kk = idx % 96;
    v = (col < 32 && kk < 65) ? Wemb1[kk * 32 + col] : 0.f;
  } else {
    const int col = idx >> 6;
    v = (col < 32) ? Wemb2[k * 32 + col] : 0.f;
  }
  wout[gid] = f2bf(v);
}

#define STAGE_W(srcbase) do { const ushort* _s = (srcbase);                      \
  _Pragma("unroll") for (int rr = 0; rr < 2; ++rr) {                             \
    const int idx_ = t + 256 * rr; const int c_ = idx_ >> 3, ko_ = idx_ & 7;     \
    *(short8v*)&Wl[c_ * STX + ko_ * 8] = *(const short8v*)&_s[c_ * 64 + ko_ * 8];\
  } } while (0)

#define WPRE_LOAD(srcbase) do { const ushort* _s = (srcbase);                    \
  wpre0 = *(const short8v*)&_s[(t >> 3) * 64 + (t & 7) * 8];                     \
  wpre1 = *(const short8v*)&_s[(32 + (t >> 3)) * 64 + (t & 7) * 8]; } while (0)

#define WPRE_STORE() do {                                                        \
  *(short8v*)&Wl[(t >> 3) * STX + (t & 7) * 8] = wpre0;                          \
  *(short8v*)&Wl[(32 + (t >> 3)) * STX + (t & 7) * 8] = wpre1; } while (0)

#define MFMA_K64() do {                                                          \
  _Pragma("unroll") for (int kb = 0; kb < 2; ++kb) {                             \
    const bf16x8 af_ = *(const bf16x8*)&Xl[(w * 16 + ll) * STX + kb * 32 + lh * 8]; \
    acc[0] = __builtin_amdgcn_mfma_f32_16x16x32_bf16(af_,                        \
        *(const bf16x8*)&Wl[(     ll) * STX + kb * 32 + lh * 8], acc[0], 0, 0, 0); \
    acc[1] = __builtin_amdgcn_mfma_f32_16x16x32_bf16(af_,                        \
        *(const bf16x8*)&Wl[(16 + ll) * STX + kb * 32 + lh * 8], acc[1], 0, 0, 0); \
    acc[2] = __builtin_amdgcn_mfma_f32_16x16x32_bf16(af_,                        \
        *(const bf16x8*)&Wl[(32 + ll) * STX + kb * 32 + lh * 8], acc[2], 0, 0, 0); \
    acc[3] = __builtin_amdgcn_mfma_f32_16x16x32_bf16(af_,                        \
        *(const bf16x8*)&Wl[(48 + ll) * STX + kb * 32 + lh * 8], acc[3], 0, 0, 0); \
  } } while (0)

#define ZERO_ACC() do { _Pragma("unroll") for (int q = 0; q < 4; ++q)            \
    acc[q] = (f32x4){0.f, 0.f, 0.f, 0.f}; } while (0)

#define PACK_STORE16(dstp) do {                                                  \
  unsigned pk[8];                                                                \
  _Pragma("unroll") for (int q = 0; q < 8; ++q)                                  \
    pk[q] = (unsigned)f2bf(xv[2 * q]) | ((unsigned)f2bf(xv[2 * q + 1]) << 16);   \
  *(uint4v*)(dstp)       = (uint4v){pk[0], pk[1], pk[2], pk[3]};                 \
  *(uint4v*)((dstp) + 8) = (uint4v){pk[4], pk[5], pk[6], pk[7]};                 \
} while (0)

// tri staging (bf16 smF); fa cached across runs; 2-way banks (free)
#define TRI16(kt) do {                                                           \
  int prev_a = -1; float fa0 = 0.f, fa1 = 0.f, fa2 = 0.f;                        \
  _Pragma("unroll") for (int m = 0; m < 16; ++m) {                               \
    const int tb = tabL[(kt) + m];                                               \
    const int a_ = tb & 31, b_ = (tb >> 8) & 31;                                 \
    if (a_ != prev_a) { fa0 = bfu(fr[a_]); fa1 = bfu(fr[32 + a_]);               \
                        fa2 = bfu(fr[64 + a_]); prev_a = a_; }                   \
    const float v = fmaf(fa0, bfu(fr[b_]),                                       \
        fmaf(fa1, bfu(fr[32 + b_]), fa2 * bfu(fr[64 + b_])));                    \
    const float wsel = (tb & 0x8000) ? 2.f : 1.f;                                \
    sumsq = fmaf(v * wsel, v, sumsq);                                            \
    xv[m] = v;                                                                   \
  } } while (0)

#define XV_LOAD16(p) do { const float* _p = (p);                                 \
  _Pragma("unroll") for (int q = 0; q < 4; ++q) {                                \
    const float4 v4 = *(const float4*)(_p + 4 * q);                              \
    xv[4 * q + 0] = v4.x; xv[4 * q + 1] = v4.y;                                  \
    xv[4 * q + 2] = v4.z; xv[4 * q + 3] = v4.w; } } while (0)

// holder-side consume: one u32 = bf16 pair (a, a+1) per i
#define CONSUME_NT() do {                                                        \
  _Pragma("unroll") for (int r = 0; r < 4; ++r) {                                \
    const int row_ = w * 16 + lh * 4 + r;                                        \
    const unsigned u0 = *(const unsigned*)&smFh[row_ * SFH +      nt * 2];       \
    const unsigned u1 = *(const unsigned*)&smFh[row_ * SFH + 32 + nt * 2];       \
    const unsigned u2 = *(const unsigned*)&smFh[row_ * SFH + 64 + nt * 2];       \
    union { unsigned x; float f; } l0, h0, l1, h1, l2, h2;                       \
    l0.x = u0 << 16; h0.x = u0 & 0xffff0000u;                                    \
    l1.x = u1 << 16; h1.x = u1 & 0xffff0000u;                                    \
    l2.x = u2 << 16; h2.x = u2 & 0xffff0000u;                                    \
    _Pragma("unroll") for (int nc = 0; nc < 4; ++nc) {                           \
      const float cv = (acc[nc][r] + b3v[nc]) * ifnr[r];                         \
      const int p = nc & 1;                                                      \
      const float f0 = (nc < 2) ? l0.f : h0.f;                                   \
      const float f1 = (nc < 2) ? l1.f : h1.f;                                   \
      const float f2 = (nc < 2) ? l2.f : h2.f;                                   \
      fch[(r * 3 + 0) * 2 + p] = fmaf(f0, cv, fch[(r * 3 + 0) * 2 + p]);         \
      fch[(r * 3 + 1) * 2 + p] = fmaf(f1, cv, fch[(r * 3 + 1) * 2 + p]);         \
      fch[(r * 3 + 2) * 2 + p] = fmaf(f2, cv, fch[(r * 3 + 2) * 2 + p]);         \
    }                                                                            \
  } } while (0)

// stage fch/cs to bf16 F/S flush buffers
#define STAGE_FS() do {                                                          \
  _Pragma("unroll") for (int r = 0; r < 4; ++r) {                                \
    const int row_ = w * 16 + lh * 4 + r;                                        \
    _Pragma("unroll") for (int i = 0; i < 3; ++i) {                              \
      F[row_ * SFB + i * 32 + ll]      = f2bf(fch[(r * 3 + i) * 2 + 0]);         \
      F[row_ * SFB + i * 32 + ll + 16] = f2bf(fch[(r * 3 + i) * 2 + 1]);         \
    }                                                                            \
    _Pragma("unroll") for (int nc = 0; nc < 4; ++nc)                             \
      S[row_ * SSB + nc * 16 + ll] = f2bf(cs[nc * 4 + r]);                       \
  } } while (0)

// LDS carve (34656 B) — R13 layout, verified
#define LDS_BYTES 34656

__global__ __launch_bounds__(256, 3)
void sgnn_edge(const float* __restrict__ f, const float* __restrict__ s,
               const float* __restrict__ edge_f, const float* __restrict__ edge_s,
               const float* __restrict__ b1, const float* __restrict__ b2,
               const float* __restrict__ b3,
               const ushort* __restrict__ wbf, const ushort* __restrict__ tab_g,
               const int* __restrict__ eidx, const int* __restrict__ sorted,
               const int* __restrict__ start_g, const int* __restrict__ deg_g,
               float* __restrict__ fc_sum, float* __restrict__ sc_sum) {
  __shared__ __align__(16) char sbuf[LDS_BYTES];
  ushort* smFh = (ushort*)sbuf;            // [64][SFH]
  ushort* F    = (ushort*)sbuf;            // flush overlay [64][SFB]
  ushort* Xl   = (ushort*)(sbuf + 13056);
  ushort* S    = (ushort*)(sbuf + 13056);  // flush overlay [64][SSB]
  ushort* Aemb = (ushort*)(sbuf + 13056);  // embed A [96][SAE]
  ushort* Wl   = (ushort*)(sbuf + 22272);
  float*  red  = (float*)(sbuf + 31488);
  int*    snode = (int*)(sbuf + 31488);    // flush meta (red dead)
  int*    srow0 = snode + 8;
  int*    srow1 = snode + 16;
  int*    sst   = snode + 24;
  int*    sdg   = snode + 32;
  ushort* tabL = (ushort*)(sbuf + 33088);
  float*  iFn  = (float*)(sbuf + 33088);   // overlays tab after GEMM1
  int*    es_s = (int*)(sbuf + 34144);
  ushort* e0s  = (ushort*)(sbuf + 34400);
  ushort* e1s  = (ushort*)(sbuf + 34528);

  const int t = threadIdx.x, j = t & 63, w = t >> 6, eb = w * 16;
  const int lh = j >> 4, ll = j & 15;
  const int bid = blockIdx.x;
  const ushort* wembT = wbf + 59 * 4096;
  short8v wpre0, wpre1;

  if (t < 64) {
    const int e = sorted[bid * 64 + t];
    es_s[t] = e;
    e0s[t] = (ushort)eidx[e];
    e1s[t] = (ushort)eidx[NE + e];
  }
  for (int idx = t; idx < NTRI; idx += 256) tabL[idx] = tab_g[idx];
  __syncthreads();

  int str = 0, dgr = 0;
  if (j < 16) {
    const int n_ = e0s[eb + j];
    str = start_g[n_];
    dgr = deg_g[n_];
  }
  WPRE_LOAD(wbf + 0);

  // ---- MFMA embed (verified R9/R10), output packed to bf16 smF ----
  #pragma unroll 1
  for (int h = 0; h < 2; ++h) {
    const int hb = h * 32;
    #pragma unroll 1
    for (int cc = t; cc < 576; cc += 256) {
      const int row = cc / 6, seg = cc - row * 6;
      const int lel = (row * 43) >> 7, il = row - lel * 3;
      const int k0 = seg * 16;
      float xv[16];
      if (seg < 4) {
        const int nd = (seg < 2) ? (int)e0s[hb + lel] : (int)e1s[hb + lel];
        XV_LOAD16(f + nd * 96 + il * 32 + (seg & 1) * 16);
      } else if (seg == 4) {
        xv[0] = edge_f[es_s[hb + lel] * 3 + il];
        #pragma unroll
        for (int m = 1; m < 16; ++m) xv[m] = 0.f;
      } else {
        #pragma unroll
        for (int m = 0; m < 16; ++m) xv[m] = 0.f;
      }
      PACK_STORE16(&Aemb[row * SAE + k0]);
    }
    __syncthreads();
    #pragma unroll 1
    for (int job = w * 3; job < w * 3 + 3; ++job) {
      const int mt = job >> 1, nt = job & 1;
      f32x4 ac = (f32x4){0.f, 0.f, 0.f, 0.f};
      #pragma unroll
      for (int kb = 0; kb < 3; ++kb) {
        const bf16x8 av = *(const bf16x8*)&Aemb[(mt * 16 + ll) * SAE + kb * 32 + lh * 8];
        const bf16x8 bv = *(const bf16x8*)&wembT[(nt * 16 + ll) * 96 + kb * 32 + lh * 8];
        ac = __builtin_amdgcn_mfma_f32_16x16x32_bf16(av, bv, ac, 0, 0, 0);
      }
      #pragma unroll
      for (int r = 0; r < 4; ++r) {
        const int rr = mt * 16 + lh * 4 + r;
        const int lel = (rr * 43) >> 7, il = rr - lel * 3;
        smFh[(hb + lel) * SFH + il * 32 + nt * 16 + ll] = f2bf(ac[r]);
      }
    }
    __syncthreads();
  }

  f32x4 acc[4];
  ZERO_ACC();
  float sumsq = 0.f;

  // ---- GEMM1: 12 K-stages ----
  #pragma unroll 1
  for (int T = 0; T < 12; ++T) {
    __syncthreads();
    WPRE_STORE();
    {
      const ushort* fr = smFh + j * SFH;
      float xv[16];
      if (T < 8) {
        TRI16(T * 64 + w * 16);
      } else if (T == 8) {
        if (w == 0) {
          TRI16(512);
        } else if (w == 1) {
          const float4 v4 = *(const float4*)(edge_s + es_s[j] * 68 + 64);
          xv[0] = v4.x; xv[1] = v4.y; xv[2] = v4.z; xv[3] = v4.w;
          #pragma unroll
          for (int m = 4; m < 16; ++m) xv[m] = 0.f;
        } else {
          #pragma unroll
          for (int m = 0; m < 16; ++m) xv[m] = 0.f;
        }
      } else if (T == 9)  { XV_LOAD16(s + e0s[j] * 64 + w * 16); }
      else if (T == 10)   { XV_LOAD16(s + e1s[j] * 64 + w * 16); }
      else                { XV_LOAD16(edge_s + es_s[j] * 68 + w * 16); }
      PACK_STORE16(&Xl[j * STX + w * 16]);
    }
    __syncthreads();
    WPRE_LOAD(wbf + (T + 1) * 4096);
    MFMA_K64();
  }

  // ---- h1 epilogue + Fn reduce ----
  __syncthreads();
  red[w * 64 + j] = sumsq;
  #pragma unroll
  for (int nc = 0; nc < 4; ++nc) {
    const float bv = b1[nc * 16 + ll];
    #pragma unroll
    for (int r = 0; r < 4; ++r)
      Xl[(w * 16 + lh * 4 + r) * STX + nc * 16 + ll] = f2bf(fmaxf(acc[nc][r] + bv, 0.f));
  }
  WPRE_STORE();
  ZERO_ACC();
  __syncthreads();
  if (t < 64) {
    const float ss = red[t] + red[64 + t] + red[128 + t] + red[192 + t];
    iFn[t] = 1.f / (sqrtf(ss) + 1.f);
  }

  // ---- GEMM2 ----
  MFMA_K64();
  #pragma unroll
  for (int nc = 0; nc < 4; ++nc) {
    const float bv = b2[nc * 16 + ll];
    #pragma unroll
    for (int r = 0; r < 4; ++r)
      Xl[(w * 16 + lh * 4 + r) * STX + nc * 16 + ll] = f2bf(fmaxf(acc[nc][r] + bv, 0.f));
  }

  // ---- GEMM3: holder-side consume (verified R10) ----
  float fch[24];
  #pragma unroll
  for (int q = 0; q < 24; ++q) fch[q] = 0.f;
  float cs[16];
  float ifnr[4];

  #pragma unroll 1
  for (int nt = 0; nt < 17; ++nt) {
    __syncthreads();
    STAGE_W(wbf + (13 + nt) * 4096);
    float b3v[4];
    #pragma unroll
    for (int nc = 0; nc < 4; ++nc) b3v[nc] = b3[nt * 64 + nc * 16 + ll];
    __syncthreads();
    if (nt == 0) {
      #pragma unroll
      for (int r = 0; r < 4; ++r) ifnr[r] = iFn[w * 16 + lh * 4 + r];
    }
    ZERO_ACC();
    MFMA_K64();
    if (nt < 16) {
      CONSUME_NT();
    } else {
      #pragma unroll
      for (int nc = 0; nc < 4; ++nc)
        #pragma unroll
        for (int r = 0; r < 4; ++r)
          cs[nc * 4 + r] = (acc[nc][r] + b3v[nc]) * ifnr[r];
    }
  }

  // ---- stage F/S (bf16), then run-flush (verified R5/R10/R11) ----
  __syncthreads();
  STAGE_FS();
  if (t < 8) snode[t] = -1;
  __syncthreads();

  {
    float r0 = 0.f, r1 = 0.f, rs = 0.f;
    int runlen = 0;
    const int gwb = bid * 64 + eb;
    #pragma unroll 1
    for (int m = 0; m < 16; ++m) {
      const int row = eb + m;
      r0 += bfu(F[row * SFB + j]);
      if (j < 32) r1 += bfu(F[row * SFB + 64 + j]);
      rs += bfu(S[row * SSB + j]);
      ++runlen;
      const int n = e0s[row];
      if (m == 15 || e0s[row + 1] != n) {
        const int st = __shfl(str, m);
        const int dg = __shfl(dgr, m);
        const int g1v = gwb + m, g0v = g1v - runlen + 1;
        if (g0v == st && runlen == dg) {
          fc_sum[n * 96 + j] = r0;
          if (j < 32) fc_sum[n * 96 + 64 + j] = r1;
          sc_sum[n * 64 + j] = rs;
        } else {
          const int slot = (g0v == gwb) ? 2 * w : 2 * w + 1;
          if (j == 0) {
            snode[slot] = n; srow0[slot] = row - runlen + 1; srow1[slot] = row;
            sst[slot] = st; sdg[slot] = dg;
          }
        }
        r0 = r1 = rs = 0.f; runlen = 0;
      }
    }
  }
  __syncthreads();

  if (t < 160) {
    const int ch = t;
    int prevn = -1;
    #pragma unroll 1
    for (int ss = 0; ss < 8; ++ss) {
      const int n = snode[ss];
      if (n < 0) continue;
      if (n != prevn) {
        float v = 0.f;
        #pragma unroll 1
        for (int k2 = ss; k2 < 8; ++k2) {
          if (snode[k2] == n) {
            #pragma unroll 1
            for (int row = srow0[k2]; row <= srow1[k2]; ++row)
              v += (ch < 96) ? bfu(F[row * SFB + ch]) : bfu(S[row * SSB + (ch - 96)]);
          } else if (k2 > ss && snode[k2] >= 0) break;
        }
        const bool cib = (sst[ss] >= bid * 64) && (sst[ss] + sdg[ss] <= bid * 64 + 64);
        float* dst = (ch < 96) ? (fc_sum + n * 96 + ch) : (sc_sum + n * 64 + (ch - 96));
        if (cib) *dst = v; else atomicAdd(dst, v);
      }
      prevn = n;
    }
  }
}

__global__ __launch_bounds__(256, 3)
void sgnn_node(const float* __restrict__ f, const float* __restrict__ s,
               const float* __restrict__ b1, const float* __restrict__ b2,
               const float* __restrict__ b3,
               const ushort* __restrict__ wbf, const ushort* __restrict__ tab_g,
               const float* __restrict__ fcm, const float* __restrict__ scm,
               const int* __restrict__ deg_g,
               float* __restrict__ of, float* __restrict__ os) {
  __shared__ __align__(16) char sbuf[LDS_BYTES];
  ushort* smFh = (ushort*)sbuf;
  ushort* F    = (ushort*)sbuf;
  ushort* Xl   = (ushort*)(sbuf + 13056);
  ushort* S    = (ushort*)(sbuf + 13056);
  ushort* Aemb = (ushort*)(sbuf + 13056);  // [96][SAN] = 13824
  ushort* Wl   = (ushort*)(sbuf + 22272);
  float*  red  = (float*)(sbuf + 31488);
  float*  icntL = (float*)(sbuf + 31488);  // dead before red written
  ushort* tabL = (ushort*)(sbuf + 33088);
  float*  iFn  = (float*)(sbuf + 33088);

  const int t = threadIdx.x, j = t & 63, w = t >> 6, eb = w * 16;
  const int lh = j >> 4, ll = j & 15;
  const int nbase = blockIdx.x * 64;
  const ushort* wembTn = wbf + 60 * 4096;
  short8v wpre0, wpre1;

  for (int idx = t; idx < NTRI; idx += 256) tabL[idx] = tab_g[idx];
  if (t < 64)
    icntL[t] = 1.f / fmaxf((float)deg_g[min(nbase + t, NN - 1)], 1.f);
  WPRE_LOAD(wbf + 30 * 4096);
  __syncthreads();

  // ---- MFMA embed: smF = concat(f, fc_sum*icnt) @ Wemb2 ----
  #pragma unroll 1
  for (int h = 0; h < 2; ++h) {
    const int hb = h * 32;
    #pragma unroll 1
    for (int cc = t; cc < 384; cc += 256) {
      const int row = cc >> 2, seg = cc & 3;
      const int lel = (row * 43) >> 7, il = row - lel * 3;
      const int nc = min(nbase + hb + lel, NN - 1);
      const int k0 = seg * 16;
      float xv[16];
      if (seg < 2) {
        XV_LOAD16(f + nc * 96 + il * 32 + seg * 16);
      } else {
        XV_LOAD16(fcm + nc * 96 + il * 32 + (seg - 2) * 16);
        const float ic = icntL[hb + lel];
        #pragma unroll
        for (int m = 0; m < 16; ++m) xv[m] *= ic;
      }
      PACK_STORE16(&Aemb[row * SAN + k0]);
    }
    __syncthreads();
    #pragma unroll 1
    for (int job = w * 3; job < w * 3 + 3; ++job) {
      const int mt = job >> 1, nt = job & 1;
      f32x4 ac = (f32x4){0.f, 0.f, 0.f, 0.f};
      #pragma unroll
      for (int kb = 0; kb < 2; ++kb) {
        const bf16x8 av = *(const bf16x8*)&Aemb[(mt * 16 + ll) * SAN + kb * 32 + lh * 8];
        const bf16x8 bv = *(const bf16x8*)&wembTn[(nt * 16 + ll) * 64 + kb * 32 + lh * 8];
        ac = __builtin_amdgcn_mfma_f32_16x16x32_bf16(av, bv, ac, 0, 0, 0);
      }
      #pragma unroll
      for (int r = 0; r < 4; ++r) {
        const int rr = mt * 16 + lh * 4 + r;
        const int lel = (rr * 43) >> 7, il = rr - lel * 3;
        smFh[(hb + lel) * SFH + il * 32 + nt * 16 + ll] = f2bf(ac[r]);
      }
    }
    __syncthreads();
  }

  f32x4 acc[4];
  ZERO_ACC();
  float sumsq = 0.f;

  // ---- GEMM1: 11 K-stages ----
  #pragma unroll 1
  for (int T = 0; T < 11; ++T) {
    __syncthreads();
    WPRE_STORE();
    {
      const ushort* fr = smFh + j * SFH;
      float xv[16];
      if (T < 8) {
        TRI16(T * 64 + w * 16);
      } else if (T == 8) {
        if (w == 0) {
          TRI16(512);
        } else {
          #pragma unroll
          for (int m = 0; m < 16; ++m) xv[m] = 0.f;
        }
      } else if (T == 9) {
        XV_LOAD16(s + min(nbase + j, NN - 1) * 64 + w * 16);
      } else {
        XV_LOAD16(scm + min(nbase + j, NN - 1) * 64 + w * 16);
        const float ic = icntL[j];
        #pragma unroll
        for (int m = 0; m < 16; ++m) xv[m] *= ic;
      }
      PACK_STORE16(&Xl[j * STX + w * 16]);
    }
    __syncthreads();
    WPRE_LOAD(wbf + (31 + T) * 4096);
    MFMA_K64();
  }

  __syncthreads();
  red[w * 64 + j] = sumsq;
  #pragma unroll
  for (int nc = 0; nc < 4; ++nc) {
    const float bv = b1[nc * 16 + ll];
    #pragma unroll
    for (int r = 0; r < 4; ++r)
      Xl[(w * 16 + lh * 4 + r) * STX + nc * 16 + ll] = f2bf(fmaxf(acc[nc][r] + bv, 0.f));
  }
  WPRE_STORE();
  ZERO_ACC();
  __syncthreads();
  if (t < 64) {
    const float ss = red[t] + red[64 + t] + red[128 + t] + red[192 + t];
    iFn[t] = 1.f / (sqrtf(ss) + 1.f);
  }

  MFMA_K64();                        // GEMM2
  #pragma unroll
  for (int nc = 0; nc < 4; ++nc) {
    const float bv = b2[nc * 16 + ll];
    #pragma unroll
    for (int r = 0; r < 4; ++r)
      Xl[(w * 16 + lh * 4 + r) * STX + nc * 16 + ll] = f2bf(fmaxf(acc[nc][r] + bv, 0.f));
  }

  // ---- GEMM3: holder-side consume ----
  float fch[24];
  #pragma unroll
  for (int q = 0; q < 24; ++q) fch[q] = 0.f;
  float cs[16];
  float ifnr[4];

  #pragma unroll 1
  for (int nt = 0; nt < 17; ++nt) {
    __syncthreads();
    STAGE_W(wbf + (42 + nt) * 4096);
    float b3v[4];
    #pragma unroll
    for (int nc = 0; nc < 4; ++nc) b3v[nc] = b3[nt * 64 + nc * 16 + ll];
    __syncthreads();
    if (nt == 0) {
      #pragma unroll
      for (int r = 0; r < 4; ++r) ifnr[r] = iFn[w * 16 + lh * 4 + r];
    }
    ZERO_ACC();
    MFMA_K64();
    if (nt < 16) {
      CONSUME_NT();
    } else {
      #pragma unroll
      for (int nc = 0; nc < 4; ++nc)
        #pragma unroll
        for (int r = 0; r < 4; ++r)
          cs[nc * 4 + r] = (acc[nc][r] + b3v[nc]) * ifnr[r];
    }
  }

  // ---- stage F/S + residual writes ----
  __syncthreads();
  STAGE_FS();
  __syncthreads();

  #pragma unroll 1
  for (int m = 0; m < 16; ++m) {
    const int row = eb + m;
    const int n_m = nbase + row;
    if (n_m < NN) {
      of[n_m * 96 + j] = bfu(F[row * SFB + j]) + f[n_m * 96 + j];
      if (j < 32)
        of[n_m * 96 + 64 + j] = bfu(F[row * SFB + 64 + j]) + f[n_m * 96 + 64 + j];
      os[n_m * 64 + j] = bfu(S[row * SSB + j]) + s[n_m * 64 + j];
    }
  }
}

extern "C" void kernel_launch(void* const* d_in, const int* in_sizes, int n_in,
                              void* d_out, int out_size, void* d_ws, size_t ws_size,
                              hipStream_t stream) {
  const float* f      = (const float*)d_in[0];
  const float* s      = (const float*)d_in[1];
  const float* edge_f = (const float*)d_in[2];
  const float* edge_s = (const float*)d_in[3];
  const float* Wemb1  = (const float*)d_in[4];
  const float* nW1 = (const float*)d_in[5];
  const float* nb1 = (const float*)d_in[6];
  const float* nW2 = (const float*)d_in[7];
  const float* nb2 = (const float*)d_in[8];
  const float* nW3 = (const float*)d_in[9];
  const float* nb3 = (const float*)d_in[10];
  const float* Wemb2 = (const float*)d_in[11];
  const float* sW1 = (const float*)d_in[12];
  const float* sb1 = (const float*)d_in[13];
  const float* sW2 = (const float*)d_in[14];
  const float* sb2 = (const float*)d_in[15];
  const float* sW3 = (const float*)d_in[16];
  const float* sb3 = (const float*)d_in[17];
  const int* eidx  = (const int*)d_in[18];

  float* of = (float*)d_out;               // [NN*96] ; holds fc sums pre-node
  float* os = of + (size_t)NN * 96;        // [NN*64] ; holds sc sums pre-node

  // ws: deg[NN] | cursor[NN] | start[NN] | sorted[NE] | wbf[61*4096] | tab[528]
  int* deg    = (int*)d_ws;
  int* cursor = deg + NN;
  int* start  = cursor + NN;
  int* sorted = start + NN;
  ushort* wbf = (ushort*)(sorted + NE);
  ushort* tab = wbf + 61 * 4096;

  hipMemsetAsync(deg, 0, (size_t)NN * 4, stream);
  hipMemsetAsync(d_out, 0, (size_t)NN * 160 * 4, stream);

  hipLaunchKernelGGL(sgnn_wconv, dim3((61 * 4096 + NTRI + 255) / 256), dim3(256),
                     0, stream, nW1, nW2, nW3, sW1, sW2, sW3, Wemb1, Wemb2,
                     eidx, deg, wbf, tab);
  hipLaunchKernelGGL(sgnn_scan, dim3(1), dim3(1024), 0, stream, deg, cursor, start);
  hipLaunchKernelGGL(sgnn_scatter, dim3((NE + 255) / 256), dim3(256), 0, stream,
                     eidx, cursor, sorted);
  hipLaunchKernelGGL(sgnn_edge, dim3(NE / 64), dim3(256), 0, stream,
                     f, s, edge_f, edge_s, nb1, nb2, nb3,
                     wbf, tab, eidx, sorted, start, deg,
                     of /*fc_sum*/, os /*sc_sum*/);
  hipLaunchKernelGGL(sgnn_node, dim3((NN + 63) / 64), dim3(256), 0, stream,
                     f, s, sb1, sb2, sb3,
                     wbf, tab, of /*fc sums*/, os /*sc sums*/, deg, of, os);
}

// Round 17
// 198.000 us; speedup vs baseline: 1.1929x; 1.0215x over previous
//
#include <hip/hip_runtime.h>
#include <math.h>

#define NN 10000
#define NE 80000
#define SFH 102  // smF bf16 stride: 204B row = 51 dwords (odd) -> 2-way max (free)
#define SFB 98   // F flush bf16 stride
#define SSB 66   // S flush bf16 stride
#define STX 72   // bf16 GEMM tile row stride
#define NTRI 528 // 32*33/2 unique Gram entries
#define SAE 104  // edge embed A stride (bf16)
#define SAN 72   // node embed A stride (bf16)

typedef __attribute__((ext_vector_type(8))) __bf16 bf16x8;
typedef __attribute__((ext_vector_type(8))) short short8v;
typedef __attribute__((ext_vector_type(4))) float f32x4;
typedef __attribute__((ext_vector_type(4))) unsigned uint4v;

__device__ __forceinline__ ushort f2bf(float x) {
  union { float f; unsigned u; } v; v.f = x;
  unsigned r = v.u + 0x7FFFu + ((v.u >> 16) & 1u);
  return (ushort)(r >> 16);
}
__device__ __forceinline__ float bfu(ushort u) {
  union { unsigned x; float f; } v; v.x = (unsigned)u << 16;
  return v.f;
}
__device__ __forceinline__ void tri_ab(int k, int& a, int& b) {
  int aa = 0, rem = k;
  while (rem >= 32 - aa) { rem -= 32 - aa; ++aa; }
  a = aa; b = aa + rem;
}

// ---- single-pass register-blocked scan (verified R15) ----
__global__ __launch_bounds__(1024)
void sgnn_scan(const int* __restrict__ deg, int* __restrict__ cursor,
               int* __restrict__ start) {
  __shared__ int sm[1024];
  const int t = threadIdx.x;
  const int i0 = t * 10;
  int v[10], pre = 0;
  #pragma unroll
  for (int q = 0; q < 10; ++q) {
    const int i = i0 + q;
    v[q] = (i < NN) ? deg[i] : 0;
    pre += v[q];
  }
  sm[t] = pre;
  __syncthreads();
  int run = pre;
  #pragma unroll
  for (int d = 1; d < 1024; d <<= 1) {
    const int add = (t >= d) ? sm[t - d] : 0;
    __syncthreads();
    run += add;
    sm[t] = run;
    __syncthreads();
  }
  int excl = run - pre;
  #pragma unroll
  for (int q = 0; q < 10; ++q) {
    const int i = i0 + q;
    if (i < NN) { cursor[i] = excl; start[i] = excl; }
    excl += v[q];
  }
}

__global__ __launch_bounds__(256)
void sgnn_scatter(const int* __restrict__ eidx, int* __restrict__ cursor,
                  int* __restrict__ sorted) {
  const int e = blockIdx.x * 256 + threadIdx.x;
  if (e < NE) {
    const int p = atomicAdd(cursor + eidx[e], 1);
    sorted[p] = e;
  }
}

// ---- weight convert + fused histogram (verified R11) ----
__global__ __launch_bounds__(256)
void sgnn_wconv(const float* __restrict__ nW1, const float* __restrict__ nW2,
                const float* __restrict__ nW3, const float* __restrict__ sW1,
                const float* __restrict__ sW2, const float* __restrict__ sW3,
                const float* __restrict__ Wemb1, const float* __restrict__ Wemb2,
                const int* __restrict__ eidx, int* __restrict__ deg,
                ushort* __restrict__ wout, ushort* __restrict__ tab) {
  const int gid = blockIdx.x * 256 + threadIdx.x;
  if (gid < NE) atomicAdd(deg + eidx[gid], 1);
  if (gid >= 61 * 4096) {
    const int k = gid - 61 * 4096;
    if (k < NTRI) {
      int a, b; tri_ab(k, a, b);
      tab[k] = (ushort)(a | (b << 8) | ((a != b) ? 0x8000 : 0));
    }
    return;
  }
  const int tile = gid >> 12, idx = gid & 4095;
  const int c = idx >> 6, k = idx & 63;
  float v = 0.f;
  if (tile < 12) {
    const int T = tile;
    if (T < 8 || (T == 8 && k < 16)) {
      const int ktri = T * 64 + k;
      if (ktri < NTRI) {
        int a, b; tri_ab(ktri, a, b);
        v = nW1[(a * 32 + b) * 64 + c];
        if (a != b) v += nW1[(b * 32 + a) * 64 + c];
      }
    } else if (T == 8) { if (k < 20) v = nW1[(1216 + (k - 16)) * 64 + c]; }
    else if (T == 9)   v = nW1[(1024 + k) * 64 + c];
    else if (T == 10)  v = nW1[(1088 + k) * 64 + c];
    else               v = nW1[(1152 + k) * 64 + c];
  } else if (tile == 12) v = nW2[k * 64 + c];
  else if (tile < 30)    v = nW3[k * 1088 + (tile - 13) * 64 + c];
  else if (tile < 41) {
    const int T = tile - 30;
    if (T < 8 || (T == 8 && k < 16)) {
      const int ktri = T * 64 + k;
      if (ktri < NTRI) {
        int a, b; tri_ab(ktri, a, b);
        v = sW1[(a * 32 + b) * 64 + c];
        if (a != b) v += sW1[(b * 32 + a) * 64 + c];
      }
    } else if (T == 9) v = sW1[(1024 + k) * 64 + c];
    else if (T == 10)  v = sW1[(1088 + k) * 64 + c];
  } else if (tile == 41) v = sW2[k * 64 + c];
  else if (tile < 59)    v = sW3[k * 1088 + (tile - 42) * 64 + c];
  else if (tile == 59) {
    const int col = idx / 96, kk = idx % 96;
    v = (col < 32 && kk < 65) ? Wemb1[kk * 32 + col] : 0.f;
  } else {
    const int col = idx >> 6;
    v = (col < 32) ? Wemb2[k * 32 + col] : 0.f;
  }
  wout[gid] = f2bf(v);
}

#define STAGE_W(srcbase) do { const ushort* _s = (srcbase);                      \
  _Pragma("unroll") for (int rr = 0; rr < 2; ++rr) {                             \
    const int idx_ = t + 256 * rr; const int c_ = idx_ >> 3, ko_ = idx_ & 7;     \
    *(short8v*)&Wl[c_ * STX + ko_ * 8] = *(const short8v*)&_s[c_ * 64 + ko_ * 8];\
  } } while (0)

#define WPRE_LOAD(srcbase) do { const ushort* _s = (srcbase);                    \
  wpre0 = *(const short8v*)&_s[(t >> 3) * 64 + (t & 7) * 8];                     \
  wpre1 = *(const short8v*)&_s[(32 + (t >> 3)) * 64 + (t & 7) * 8]; } while (0)

#define WPRE_STORE() do {                                                        \
  *(short8v*)&Wl[(t >> 3) * STX + (t & 7) * 8] = wpre0;                          \
  *(short8v*)&Wl[(32 + (t >> 3)) * STX + (t & 7) * 8] = wpre1; } while (0)

// MFMA with A-fragments in registers (GEMM1)
#define MFMA_K64_RA() do {                                                       \
  acc[0] = __builtin_amdgcn_mfma_f32_16x16x32_bf16(af0.v8,                       \
      *(const bf16x8*)&Wl[(     ll) * STX + lh * 8], acc[0], 0, 0, 0);           \
  acc[1] = __builtin_amdgcn_mfma_f32_16x16x32_bf16(af0.v8,                       \
      *(const bf16x8*)&Wl[(16 + ll) * STX + lh * 8], acc[1], 0, 0, 0);           \
  acc[2] = __builtin_amdgcn_mfma_f32_16x16x32_bf16(af0.v8,                       \
      *(const bf16x8*)&Wl[(32 + ll) * STX + lh * 8], acc[2], 0, 0, 0);           \
  acc[3] = __builtin_amdgcn_mfma_f32_16x16x32_bf16(af0.v8,                       \
      *(const bf16x8*)&Wl[(48 + ll) * STX + lh * 8], acc[3], 0, 0, 0);           \
  acc[0] = __builtin_amdgcn_mfma_f32_16x16x32_bf16(af1.v8,                       \
      *(const bf16x8*)&Wl[(     ll) * STX + 32 + lh * 8], acc[0], 0, 0, 0);      \
  acc[1] = __builtin_amdgcn_mfma_f32_16x16x32_bf16(af1.v8,                       \
      *(const bf16x8*)&Wl[(16 + ll) * STX + 32 + lh * 8], acc[1], 0, 0, 0);      \
  acc[2] = __builtin_amdgcn_mfma_f32_16x16x32_bf16(af1.v8,                       \
      *(const bf16x8*)&Wl[(32 + ll) * STX + 32 + lh * 8], acc[2], 0, 0, 0);      \
  acc[3] = __builtin_amdgcn_mfma_f32_16x16x32_bf16(af1.v8,                       \
      *(const bf16x8*)&Wl[(48 + ll) * STX + 32 + lh * 8], acc[3], 0, 0, 0);      \
} while (0)

// MFMA reading X from LDS (GEMM2/GEMM3, verified)
#define MFMA_K64() do {                                                          \
  _Pragma("unroll") for (int kb = 0; kb < 2; ++kb) {                             \
    const bf16x8 af_ = *(const bf16x8*)&Xl[(w * 16 + ll) * STX + kb * 32 + lh * 8]; \
    acc[0] = __builtin_amdgcn_mfma_f32_16x16x32_bf16(af_,                        \
        *(const bf16x8*)&Wl[(     ll) * STX + kb * 32 + lh * 8], acc[0], 0, 0, 0); \
    acc[1] = __builtin_amdgcn_mfma_f32_16x16x32_bf16(af_,                        \
        *(const bf16x8*)&Wl[(16 + ll) * STX + kb * 32 + lh * 8], acc[1], 0, 0, 0); \
    acc[2] = __builtin_amdgcn_mfma_f32_16x16x32_bf16(af_,                        \
        *(const bf16x8*)&Wl[(32 + ll) * STX + kb * 32 + lh * 8], acc[2], 0, 0, 0); \
    acc[3] = __builtin_amdgcn_mfma_f32_16x16x32_bf16(af_,                        \
        *(const bf16x8*)&Wl[(48 + ll) * STX + kb * 32 + lh * 8], acc[3], 0, 0, 0); \
  } } while (0)

#define ZERO_ACC() do { _Pragma("unroll") for (int q = 0; q < 4; ++q)            \
    acc[q] = (f32x4){0.f, 0.f, 0.f, 0.f}; } while (0)

#define PACK_STORE16(dstp) do {                                                  \
  unsigned pk[8];                                                                \
  _Pragma("unroll") for (int q = 0; q < 8; ++q)                                  \
    pk[q] = (unsigned)f2bf(xv[2 * q]) | ((unsigned)f2bf(xv[2 * q + 1]) << 16);   \
  *(uint4v*)(dstp)       = (uint4v){pk[0], pk[1], pk[2], pk[3]};                 \
  *(uint4v*)((dstp) + 8) = (uint4v){pk[4], pk[5], pk[6], pk[7]};                 \
} while (0)

// pack xv[16] -> two register A-fragments
#define PACK_AF() do {                                                           \
  _Pragma("unroll") for (int q2 = 0; q2 < 4; ++q2) {                             \
    af0.u[q2] = (unsigned)f2bf(xv[2 * q2]) | ((unsigned)f2bf(xv[2 * q2 + 1]) << 16); \
    af1.u[q2] = (unsigned)f2bf(xv[8 + 2 * q2]) | ((unsigned)f2bf(xv[8 + 2 * q2 + 1]) << 16); \
  } } while (0)

// tri for 8 own-row elements at kt (contiguous); a cached across run
#define TRI8(kt, off) do {                                                       \
  int prev_a = -1; float fa0 = 0.f, fa1 = 0.f, fa2 = 0.f;                        \
  _Pragma("unroll") for (int q = 0; q < 8; ++q) {                                \
    const int tb = tabL[(kt) + q];                                               \
    const int a_ = tb & 31, b_ = (tb >> 8) & 31;                                 \
    if (a_ != prev_a) { fa0 = bfu(frA[a_]); fa1 = bfu(frA[32 + a_]);             \
                        fa2 = bfu(frA[64 + a_]); prev_a = a_; }                  \
    const float v = fmaf(fa0, bfu(frA[b_]),                                      \
        fmaf(fa1, bfu(frA[32 + b_]), fa2 * bfu(frA[64 + b_])));                  \
    const float wsel = (tb & 0x8000) ? 2.f : 1.f;                                \
    sumsq = fmaf(v * wsel, v, sumsq);                                            \
    xv[(off) + q] = v;                                                           \
  } } while (0)

#define XV8_LOAD(p, off) do { const float* _p = (p);                             \
  const float4 va = *(const float4*)(_p);                                        \
  const float4 vb = *(const float4*)(_p + 4);                                    \
  xv[(off)+0]=va.x; xv[(off)+1]=va.y; xv[(off)+2]=va.z; xv[(off)+3]=va.w;        \
  xv[(off)+4]=vb.x; xv[(off)+5]=vb.y; xv[(off)+6]=vb.z; xv[(off)+7]=vb.w;        \
} while (0)

#define XV_LOAD16(p) do { const float* _p = (p);                                 \
  _Pragma("unroll") for (int q = 0; q < 4; ++q) {                                \
    const float4 v4 = *(const float4*)(_p + 4 * q);                              \
    xv[4 * q + 0] = v4.x; xv[4 * q + 1] = v4.y;                                  \
    xv[4 * q + 2] = v4.z; xv[4 * q + 3] = v4.w; } } while (0)

// holder-side consume (verified R10/R11)
#define CONSUME_NT() do {                                                        \
  _Pragma("unroll") for (int r = 0; r < 4; ++r) {                                \
    const int row_ = w * 16 + lh * 4 + r;                                        \
    const unsigned u0 = *(const unsigned*)&smFh[row_ * SFH +      nt * 2];       \
    const unsigned u1 = *(const unsigned*)&smFh[row_ * SFH + 32 + nt * 2];       \
    const unsigned u2 = *(const unsigned*)&smFh[row_ * SFH + 64 + nt * 2];       \
    union { unsigned x; float f; } l0, h0, l1, h1, l2, h2;                       \
    l0.x = u0 << 16; h0.x = u0 & 0xffff0000u;                                    \
    l1.x = u1 << 16; h1.x = u1 & 0xffff0000u;                                    \
    l2.x = u2 << 16; h2.x = u2 & 0xffff0000u;                                    \
    _Pragma("unroll") for (int nc = 0; nc < 4; ++nc) {                           \
      const float cv = (acc[nc][r] + b3v[nc]) * ifnr[r];                         \
      const int p = nc & 1;                                                      \
      const float f0 = (nc < 2) ? l0.f : h0.f;                                   \
      const float f1 = (nc < 2) ? l1.f : h1.f;                                   \
      const float f2 = (nc < 2) ? l2.f : h2.f;                                   \
      fch[(r * 3 + 0) * 2 + p] = fmaf(f0, cv, fch[(r * 3 + 0) * 2 + p]);         \
      fch[(r * 3 + 1) * 2 + p] = fmaf(f1, cv, fch[(r * 3 + 1) * 2 + p]);         \
      fch[(r * 3 + 2) * 2 + p] = fmaf(f2, cv, fch[(r * 3 + 2) * 2 + p]);         \
    }                                                                            \
  } } while (0)

#define STAGE_FS() do {                                                          \
  _Pragma("unroll") for (int r = 0; r < 4; ++r) {                                \
    const int row_ = w * 16 + lh * 4 + r;                                        \
    _Pragma("unroll") for (int i = 0; i < 3; ++i) {                              \
      F[row_ * SFB + i * 32 + ll]      = f2bf(fch[(r * 3 + i) * 2 + 0]);         \
      F[row_ * SFB + i * 32 + ll + 16] = f2bf(fch[(r * 3 + i) * 2 + 1]);         \
    }                                                                            \
    _Pragma("unroll") for (int nc = 0; nc < 4; ++nc)                             \
      S[row_ * SSB + nc * 16 + ll] = f2bf(cs[nc * 4 + r]);                       \
  } } while (0)

// LDS carve (34656 B) — R13/R15 layout, verified
#define LDS_BYTES 34656

__global__ __launch_bounds__(256, 3)
void sgnn_edge(const float* __restrict__ f, const float* __restrict__ s,
               const float* __restrict__ edge_f, const float* __restrict__ edge_s,
               const float* __restrict__ b1, const float* __restrict__ b2,
               const float* __restrict__ b3,
               const ushort* __restrict__ wbf, const ushort* __restrict__ tab_g,
               const int* __restrict__ eidx, const int* __restrict__ sorted,
               const int* __restrict__ start_g, const int* __restrict__ deg_g,
               float* __restrict__ fc_sum, float* __restrict__ sc_sum) {
  __shared__ __align__(16) char sbuf[LDS_BYTES];
  ushort* smFh = (ushort*)sbuf;            // [64][SFH]
  ushort* F    = (ushort*)sbuf;            // flush overlay [64][SFB]
  ushort* Xl   = (ushort*)(sbuf + 13056);  // h1/h2 only
  ushort* S    = (ushort*)(sbuf + 13056);  // flush overlay [64][SSB]
  ushort* Aemb = (ushort*)(sbuf + 13056);  // embed A [96][SAE]
  ushort* Wl   = (ushort*)(sbuf + 22272);
  int*    snode = (int*)(sbuf + 31488);    // flush meta
  int*    srow0 = snode + 8;
  int*    srow1 = snode + 16;
  int*    sst   = snode + 24;
  int*    sdg   = snode + 32;
  ushort* tabL = (ushort*)(sbuf + 33088);
  float*  iFn  = (float*)(sbuf + 33088);   // overlays tab after GEMM1
  int*    es_s = (int*)(sbuf + 34144);
  ushort* e0s  = (ushort*)(sbuf + 34400);
  ushort* e1s  = (ushort*)(sbuf + 34528);

  const int t = threadIdx.x, j = t & 63, w = t >> 6, eb = w * 16;
  const int lh = j >> 4, ll = j & 15;
  const int bid = blockIdx.x;
  const ushort* wembT = wbf + 59 * 4096;
  short8v wpre0, wpre1;

  if (t < 64) {
    const int e = sorted[bid * 64 + t];
    es_s[t] = e;
    e0s[t] = (ushort)eidx[e];
    e1s[t] = (ushort)eidx[NE + e];
  }
  for (int idx = t; idx < NTRI; idx += 256) tabL[idx] = tab_g[idx];
  __syncthreads();

  int str = 0, dgr = 0;
  if (j < 16) {
    const int n_ = e0s[eb + j];
    str = start_g[n_];
    dgr = deg_g[n_];
  }
  WPRE_LOAD(wbf + 0);

  // ---- MFMA embed (verified R9-R15) ----
  #pragma unroll 1
  for (int h = 0; h < 2; ++h) {
    const int hb = h * 32;
    #pragma unroll 1
    for (int cc = t; cc < 576; cc += 256) {
      const int row = cc / 6, seg = cc - row * 6;
      const int lel = (row * 43) >> 7, il = row - lel * 3;
      const int k0 = seg * 16;
      float xv[16];
      if (seg < 4) {
        const int nd = (seg < 2) ? (int)e0s[hb + lel] : (int)e1s[hb + lel];
        XV_LOAD16(f + nd * 96 + il * 32 + (seg & 1) * 16);
      } else if (seg == 4) {
        xv[0] = edge_f[es_s[hb + lel] * 3 + il];
        #pragma unroll
        for (int m = 1; m < 16; ++m) xv[m] = 0.f;
      } else {
        #pragma unroll
        for (int m = 0; m < 16; ++m) xv[m] = 0.f;
      }
      PACK_STORE16(&Aemb[row * SAE + k0]);
    }
    __syncthreads();
    #pragma unroll 1
    for (int job = w * 3; job < w * 3 + 3; ++job) {
      const int mt = job >> 1, nt = job & 1;
      f32x4 ac = (f32x4){0.f, 0.f, 0.f, 0.f};
      #pragma unroll
      for (int kb = 0; kb < 3; ++kb) {
        const bf16x8 av = *(const bf16x8*)&Aemb[(mt * 16 + ll) * SAE + kb * 32 + lh * 8];
        const bf16x8 bv = *(const bf16x8*)&wembT[(nt * 16 + ll) * 96 + kb * 32 + lh * 8];
        ac = __builtin_amdgcn_mfma_f32_16x16x32_bf16(av, bv, ac, 0, 0, 0);
      }
      #pragma unroll
      for (int r = 0; r < 4; ++r) {
        const int rr = mt * 16 + lh * 4 + r;
        const int lel = (rr * 43) >> 7, il = rr - lel * 3;
        smFh[(hb + lel) * SFH + il * 32 + nt * 16 + ll] = f2bf(ac[r]);
      }
    }
    __syncthreads();
  }

  f32x4 acc[4];
  ZERO_ACC();
  float sumsq = 0.f;
  const int rowA = w * 16 + ll;            // this thread's A-fragment row
  const ushort* frA = smFh + rowA * SFH;

  // ---- GEMM1: 12 K-stages, A-fragments built in registers ----
  #pragma unroll 1
  for (int T = 0; T < 12; ++T) {
    float xv[16];
    union { unsigned u[4]; bf16x8 v8; } af0, af1;
    if (T < 8) {
      TRI8(T * 64 + lh * 8, 0);
      TRI8(T * 64 + 32 + lh * 8, 8);
    } else if (T == 8) {
      #pragma unroll
      for (int kb2 = 0; kb2 < 2; ++kb2)
        #pragma unroll
        for (int q = 0; q < 8; ++q) {
          const int k = kb2 * 32 + lh * 8 + q;
          float v = 0.f;
          if (k < 16) {
            const int tb = tabL[512 + k];
            const int a_ = tb & 31, b_ = (tb >> 8) & 31;
            v = fmaf(bfu(frA[a_]), bfu(frA[b_]),
                fmaf(bfu(frA[32 + a_]), bfu(frA[32 + b_]),
                     bfu(frA[64 + a_]) * bfu(frA[64 + b_])));
            const float wsel = (tb & 0x8000) ? 2.f : 1.f;
            sumsq = fmaf(v * wsel, v, sumsq);
          } else if (k < 20) {
            v = edge_s[es_s[rowA] * 68 + 64 + (k - 16)];
          }
          xv[kb2 * 8 + q] = v;
        }
    } else {
      const float* p = (T == 9)  ? (s + e0s[rowA] * 64)
                     : (T == 10) ? (s + e1s[rowA] * 64)
                                 : (edge_s + es_s[rowA] * 68);
      XV8_LOAD(p + lh * 8, 0);
      XV8_LOAD(p + 32 + lh * 8, 8);
    }
    PACK_AF();
    __syncthreads();                 // prior MFMA done reading Wl
    WPRE_STORE();                    // W(T)
    __syncthreads();
    WPRE_LOAD(wbf + (T + 1) * 4096); // T=11 -> tile 12 (W2)
    MFMA_K64_RA();
  }

  // ---- sumsq reduce (wave-local rows) + h1 epilogue ----
  {
    float ss = sumsq;
    ss += __shfl_xor(ss, 16);
    ss += __shfl_xor(ss, 32);
    __syncthreads();                 // last MFMA done reading Wl; tab dead
    if (j < 16) iFn[eb + j] = 1.f / (sqrtf(ss) + 1.f);
  }
  #pragma unroll
  for (int nc = 0; nc < 4; ++nc) {
    const float bv = b1[nc * 16 + ll];
    #pragma unroll
    for (int r = 0; r < 4; ++r)
      Xl[(w * 16 + lh * 4 + r) * STX + nc * 16 + ll] = f2bf(fmaxf(acc[nc][r] + bv, 0.f));
  }
  WPRE_STORE();                      // W2
  ZERO_ACC();
  __syncthreads();
  WPRE_LOAD(wbf + 13 * 4096);        // W3 tile 0

  // ---- GEMM2 ----
  MFMA_K64();
  #pragma unroll
  for (int nc = 0; nc < 4; ++nc) {
    const float bv = b2[nc * 16 + ll];
    #pragma unroll
    for (int r = 0; r < 4; ++r)
      Xl[(w * 16 + lh * 4 + r) * STX + nc * 16 + ll] = f2bf(fmaxf(acc[nc][r] + bv, 0.f));
  }

  // ---- GEMM3: holder-side consume (verified R10-R15) ----
  float fch[24];
  #pragma unroll
  for (int q = 0; q < 24; ++q) fch[q] = 0.f;
  float cs[16];
  float ifnr[4];

  #pragma unroll 1
  for (int nt = 0; nt < 17; ++nt) {
    __syncthreads();
    WPRE_STORE();                    // tile 13+nt
    float b3v[4];
    #pragma unroll
    for (int nc = 0; nc < 4; ++nc) b3v[nc] = b3[nt * 64 + nc * 16 + ll];
    __syncthreads();
    if (nt < 16) WPRE_LOAD(wbf + (14 + nt) * 4096);
    if (nt == 0) {
      #pragma unroll
      for (int r = 0; r < 4; ++r) ifnr[r] = iFn[w * 16 + lh * 4 + r];
    }
    ZERO_ACC();
    MFMA_K64();
    if (nt < 16) {
      CONSUME_NT();
    } else {
      #pragma unroll
      for (int nc = 0; nc < 4; ++nc)
        #pragma unroll
        for (int r = 0; r < 4; ++r)
          cs[nc * 4 + r] = (acc[nc][r] + b3v[nc]) * ifnr[r];
    }
  }

  // ---- stage F/S (bf16), then run-flush (verified R5/R10/R11) ----
  __syncthreads();
  STAGE_FS();
  if (t < 8) snode[t] = -1;
  __syncthreads();

  {
    float r0 = 0.f, r1 = 0.f, rs = 0.f;
    int runlen = 0;
    const int gwb = bid * 64 + eb;
    #pragma unroll 1
    for (int m = 0; m < 16; ++m) {
      const int row = eb + m;
      r0 += bfu(F[row * SFB + j]);
      if (j < 32) r1 += bfu(F[row * SFB + 64 + j]);
      rs += bfu(S[row * SSB + j]);
      ++runlen;
      const int n = e0s[row];
      if (m == 15 || e0s[row + 1] != n) {
        const int st = __shfl(str, m);
        const int dg = __shfl(dgr, m);
        const int g1v = gwb + m, g0v = g1v - runlen + 1;
        if (g0v == st && runlen == dg) {
          fc_sum[n * 96 + j] = r0;
          if (j < 32) fc_sum[n * 96 + 64 + j] = r1;
          sc_sum[n * 64 + j] = rs;
        } else {
          const int slot = (g0v == gwb) ? 2 * w : 2 * w + 1;
          if (j == 0) {
            snode[slot] = n; srow0[slot] = row - runlen + 1; srow1[slot] = row;
            sst[slot] = st; sdg[slot] = dg;
          }
        }
        r0 = r1 = rs = 0.f; runlen = 0;
      }
    }
  }
  __syncthreads();

  if (t < 160) {
    const int ch = t;
    int prevn = -1;
    #pragma unroll 1
    for (int ss = 0; ss < 8; ++ss) {
      const int n = snode[ss];
      if (n < 0) continue;
      if (n != prevn) {
        float v = 0.f;
        #pragma unroll 1
        for (int k2 = ss; k2 < 8; ++k2) {
          if (snode[k2] == n) {
            #pragma unroll 1
            for (int row = srow0[k2]; row <= srow1[k2]; ++row)
              v += (ch < 96) ? bfu(F[row * SFB + ch]) : bfu(S[row * SSB + (ch - 96)]);
          } else if (k2 > ss && snode[k2] >= 0) break;
        }
        const bool cib = (sst[ss] >= bid * 64) && (sst[ss] + sdg[ss] <= bid * 64 + 64);
        float* dst = (ch < 96) ? (fc_sum + n * 96 + ch) : (sc_sum + n * 64 + (ch - 96));
        if (cib) *dst = v; else atomicAdd(dst, v);
      }
      prevn = n;
    }
  }
}

__global__ __launch_bounds__(256, 3)
void sgnn_node(const float* __restrict__ f, const float* __restrict__ s,
               const float* __restrict__ b1, const float* __restrict__ b2,
               const float* __restrict__ b3,
               const ushort* __restrict__ wbf, const ushort* __restrict__ tab_g,
               const float* __restrict__ fcm, const float* __restrict__ scm,
               const int* __restrict__ deg_g,
               float* __restrict__ of, float* __restrict__ os) {
  __shared__ __align__(16) char sbuf[LDS_BYTES];
  ushort* smFh = (ushort*)sbuf;
  ushort* F    = (ushort*)sbuf;
  ushort* Xl   = (ushort*)(sbuf + 13056);
  ushort* S    = (ushort*)(sbuf + 13056);
  ushort* Aemb = (ushort*)(sbuf + 13056);
  ushort* Wl   = (ushort*)(sbuf + 22272);
  float*  icntL = (float*)(sbuf + 31488);
  ushort* tabL = (ushort*)(sbuf + 33088);
  float*  iFn  = (float*)(sbuf + 33088);

  const int t = threadIdx.x, j = t & 63, w = t >> 6, eb = w * 16;
  const int lh = j >> 4, ll = j & 15;
  const int nbase = blockIdx.x * 64;
  const ushort* wembTn = wbf + 60 * 4096;
  short8v wpre0, wpre1;

  for (int idx = t; idx < NTRI; idx += 256) tabL[idx] = tab_g[idx];
  if (t < 64)
    icntL[t] = 1.f / fmaxf((float)deg_g[min(nbase + t, NN - 1)], 1.f);
  WPRE_LOAD(wbf + 30 * 4096);
  __syncthreads();

  // ---- MFMA embed ----
  #pragma unroll 1
  for (int h = 0; h < 2; ++h) {
    const int hb = h * 32;
    #pragma unroll 1
    for (int cc = t; cc < 384; cc += 256) {
      const int row = cc >> 2, seg = cc & 3;
      const int lel = (row * 43) >> 7, il = row - lel * 3;
      const int nc = min(nbase + hb + lel, NN - 1);
      const int k0 = seg * 16;
      float xv[16];
      if (seg < 2) {
        XV_LOAD16(f + nc * 96 + il * 32 + seg * 16);
      } else {
        XV_LOAD16(fcm + nc * 96 + il * 32 + (seg - 2) * 16);
        const float ic = icntL[hb + lel];
        #pragma unroll
        for (int m = 0; m < 16; ++m) xv[m] *= ic;
      }
      PACK_STORE16(&Aemb[row * SAN + k0]);
    }
    __syncthreads();
    #pragma unroll 1
    for (int job = w * 3; job < w * 3 + 3; ++job) {
      const int mt = job >> 1, nt = job & 1;
      f32x4 ac = (f32x4){0.f, 0.f, 0.f, 0.f};
      #pragma unroll
      for (int kb = 0; kb < 2; ++kb) {
        const bf16x8 av = *(const bf16x8*)&Aemb[(mt * 16 + ll) * SAN + kb * 32 + lh * 8];
        const bf16x8 bv = *(const bf16x8*)&wembTn[(nt * 16 + ll) * 64 + kb * 32 + lh * 8];
        ac = __builtin_amdgcn_mfma_f32_16x16x32_bf16(av, bv, ac, 0, 0, 0);
      }
      #pragma unroll
      for (int r = 0; r < 4; ++r) {
        const int rr = mt * 16 + lh * 4 + r;
        const int lel = (rr * 43) >> 7, il = rr - lel * 3;
        smFh[(hb + lel) * SFH + il * 32 + nt * 16 + ll] = f2bf(ac[r]);
      }
    }
    __syncthreads();
  }

  f32x4 acc[4];
  ZERO_ACC();
  float sumsq = 0.f;
  const int rowA = w * 16 + ll;
  const ushort* frA = smFh + rowA * SFH;
  const int ncA = min(nbase + rowA, NN - 1);

  // ---- GEMM1: 11 K-stages, register A-fragments ----
  #pragma unroll 1
  for (int T = 0; T < 11; ++T) {
    float xv[16];
    union { unsigned u[4]; bf16x8 v8; } af0, af1;
    if (T < 8) {
      TRI8(T * 64 + lh * 8, 0);
      TRI8(T * 64 + 32 + lh * 8, 8);
    } else if (T == 8) {
      #pragma unroll
      for (int kb2 = 0; kb2 < 2; ++kb2)
        #pragma unroll
        for (int q = 0; q < 8; ++q) {
          const int k = kb2 * 32 + lh * 8 + q;
          float v = 0.f;
          if (k < 16) {
            const int tb = tabL[512 + k];
            const int a_ = tb & 31, b_ = (tb >> 8) & 31;
            v = fmaf(bfu(frA[a_]), bfu(frA[b_]),
                fmaf(bfu(frA[32 + a_]), bfu(frA[32 + b_]),
                     bfu(frA[64 + a_]) * bfu(frA[64 + b_])));
            const float wsel = (tb & 0x8000) ? 2.f : 1.f;
            sumsq = fmaf(v * wsel, v, sumsq);
          }
          xv[kb2 * 8 + q] = v;
        }
    } else if (T == 9) {
      XV8_LOAD(s + ncA * 64 + lh * 8, 0);
      XV8_LOAD(s + ncA * 64 + 32 + lh * 8, 8);
    } else {
      const float ic = icntL[rowA];
      XV8_LOAD(scm + ncA * 64 + lh * 8, 0);
      XV8_LOAD(scm + ncA * 64 + 32 + lh * 8, 8);
      #pragma unroll
      for (int m = 0; m < 16; ++m) xv[m] *= ic;
    }
    PACK_AF();
    __syncthreads();
    WPRE_STORE();                    // tile 30+T
    __syncthreads();
    WPRE_LOAD(wbf + (31 + T) * 4096); // T=10 -> tile 41 (W2)
    MFMA_K64_RA();
  }

  {
    float ss = sumsq;
    ss += __shfl_xor(ss, 16);
    ss += __shfl_xor(ss, 32);
    __syncthreads();
    if (j < 16) iFn[eb + j] = 1.f / (sqrtf(ss) + 1.f);
  }
  #pragma unroll
  for (int nc = 0; nc < 4; ++nc) {
    const float bv = b1[nc * 16 + ll];
    #pragma unroll
    for (int r = 0; r < 4; ++r)
      Xl[(w * 16 + lh * 4 + r) * STX + nc * 16 + ll] = f2bf(fmaxf(acc[nc][r] + bv, 0.f));
  }
  WPRE_STORE();                      // W2
  ZERO_ACC();
  __syncthreads();
  WPRE_LOAD(wbf + 42 * 4096);        // W3 tile 0

  MFMA_K64();                        // GEMM2
  #pragma unroll
  for (int nc = 0; nc < 4; ++nc) {
    const float bv = b2[nc * 16 + ll];
    #pragma unroll
    for (int r = 0; r < 4; ++r)
      Xl[(w * 16 + lh * 4 + r) * STX + nc * 16 + ll] = f2bf(fmaxf(acc[nc][r] + bv, 0.f));
  }

  // ---- GEMM3 ----
  float fch[24];
  #pragma unroll
  for (int q = 0; q < 24; ++q) fch[q] = 0.f;
  float cs[16];
  float ifnr[4];

  #pragma unroll 1
  for (int nt = 0; nt < 17; ++nt) {
    __syncthreads();
    WPRE_STORE();                    // tile 42+nt
    float b3v[4];
    #pragma unroll
    for (int nc = 0; nc < 4; ++nc) b3v[nc] = b3[nt * 64 + nc * 16 + ll];
    __syncthreads();
    if (nt < 16) WPRE_LOAD(wbf + (43 + nt) * 4096);
    if (nt == 0) {
      #pragma unroll
      for (int r = 0; r < 4; ++r) ifnr[r] = iFn[w * 16 + lh * 4 + r];
    }
    ZERO_ACC();
    MFMA_K64();
    if (nt < 16) {
      CONSUME_NT();
    } else {
      #pragma unroll
      for (int nc = 0; nc < 4; ++nc)
        #pragma unroll
        for (int r = 0; r < 4; ++r)
          cs[nc * 4 + r] = (acc[nc][r] + b3v[nc]) * ifnr[r];
    }
  }

  // ---- stage F/S + residual writes ----
  __syncthreads();
  STAGE_FS();
  __syncthreads();

  #pragma unroll 1
  for (int m = 0; m < 16; ++m) {
    const int row = eb + m;
    const int n_m = nbase + row;
    if (n_m < NN) {
      of[n_m * 96 + j] = bfu(F[row * SFB + j]) + f[n_m * 96 + j];
      if (j < 32)
        of[n_m * 96 + 64 + j] = bfu(F[row * SFB + 64 + j]) + f[n_m * 96 + 64 + j];
      os[n_m * 64 + j] = bfu(S[row * SSB + j]) + s[n_m * 64 + j];
    }
  }
}

extern "C" void kernel_launch(void* const* d_in, const int* in_sizes, int n_in,
                              void* d_out, int out_size, void* d_ws, size_t ws_size,
                              hipStream_t stream) {
  const float* f      = (const float*)d_in[0];
  const float* s      = (const float*)d_in[1];
  const float* edge_f = (const float*)d_in[2];
  const float* edge_s = (const float*)d_in[3];
  const float* Wemb1  = (const float*)d_in[4];
  const float* nW1 = (const float*)d_in[5];
  const float* nb1 = (const float*)d_in[6];
  const float* nW2 = (const float*)d_in[7];
  const float* nb2 = (const float*)d_in[8];
  const float* nW3 = (const float*)d_in[9];
  const float* nb3 = (const float*)d_in[10];
  const float* Wemb2 = (const float*)d_in[11];
  const float* sW1 = (const float*)d_in[12];
  const float* sb1 = (const float*)d_in[13];
  const float* sW2 = (const float*)d_in[14];
  const float* sb2 = (const float*)d_in[15];
  const float* sW3 = (const float*)d_in[16];
  const float* sb3 = (const float*)d_in[17];
  const int* eidx  = (const int*)d_in[18];

  float* of = (float*)d_out;
  float* os = of + (size_t)NN * 96;

  int* deg    = (int*)d_ws;
  int* cursor = deg + NN;
  int* start  = cursor + NN;
  int* sorted = start + NN;
  ushort* wbf = (ushort*)(sorted + NE);
  ushort* tab = wbf + 61 * 4096;

  hipMemsetAsync(deg, 0, (size_t)NN * 4, stream);
  hipMemsetAsync(d_out, 0, (size_t)NN * 160 * 4, stream);

  hipLaunchKernelGGL(sgnn_wconv, dim3((61 * 4096 + NTRI + 255) / 256), dim3(256),
                     0, stream, nW1, nW2, nW3, sW1, sW2, sW3, Wemb1, Wemb2,
                     eidx, deg, wbf, tab);
  hipLaunchKernelGGL(sgnn_scan, dim3(1), dim3(1024), 0, stream, deg, cursor, start);
  hipLaunchKernelGGL(sgnn_scatter, dim3((NE + 255) / 256), dim3(256), 0, stream,
                     eidx, cursor, sorted);
  hipLaunchKernelGGL(sgnn_edge, dim3(NE / 64), dim3(256), 0, stream,
                     f, s, edge_f, edge_s, nb1, nb2, nb3,
                     wbf, tab, eidx, sorted, start, deg,
                     of /*fc_sum*/, os /*sc_sum*/);
  hipLaunchKernelGGL(sgnn_node, dim3((NN + 63) / 64), dim3(256), 0, stream,
                     f, s, sb1, sb2, sb3,
                     wbf, tab, of /*fc sums*/, os /*sc sums*/, deg, of, os);
}

// Round 18
// 194.988 us; speedup vs baseline: 1.2113x; 1.0154x over previous
//
#include <hip/hip_runtime.h>
#include <math.h>

#define NN 10000
#define NE 80000
#define SFH 102  // smF bf16 stride (free 2-way banks)
#define SFB 98   // F flush bf16 stride
#define SSB 66   // S flush bf16 stride
#define STX 72   // bf16 GEMM tile row stride
#define NTRI 528
#define SAE 104  // edge embed A stride (bf16)
#define SAN 72   // node embed A stride (bf16)

typedef __attribute__((ext_vector_type(8))) __bf16 bf16x8;
typedef __attribute__((ext_vector_type(8))) short short8v;
typedef __attribute__((ext_vector_type(4))) float f32x4;
typedef __attribute__((ext_vector_type(4))) unsigned uint4v;

__device__ __forceinline__ ushort f2bf(float x) {
  union { float f; unsigned u; } v; v.f = x;
  unsigned r = v.u + 0x7FFFu + ((v.u >> 16) & 1u);
  return (ushort)(r >> 16);
}
__device__ __forceinline__ float bfu(ushort u) {
  union { unsigned x; float f; } v; v.x = (unsigned)u << 16;
  return v.f;
}
__device__ __forceinline__ void tri_ab(int k, int& a, int& b) {
  int aa = 0, rem = k;
  while (rem >= 32 - aa) { rem -= 32 - aa; ++aa; }
  a = aa; b = aa + rem;
}

// ---- single-pass register-blocked scan (verified R15) ----
__global__ __launch_bounds__(1024)
void sgnn_scan(const int* __restrict__ deg, int* __restrict__ cursor,
               int* __restrict__ start) {
  __shared__ int sm[1024];
  const int t = threadIdx.x;
  const int i0 = t * 10;
  int v[10], pre = 0;
  #pragma unroll
  for (int q = 0; q < 10; ++q) {
    const int i = i0 + q;
    v[q] = (i < NN) ? deg[i] : 0;
    pre += v[q];
  }
  sm[t] = pre;
  __syncthreads();
  int run = pre;
  #pragma unroll
  for (int d = 1; d < 1024; d <<= 1) {
    const int add = (t >= d) ? sm[t - d] : 0;
    __syncthreads();
    run += add;
    sm[t] = run;
    __syncthreads();
  }
  int excl = run - pre;
  #pragma unroll
  for (int q = 0; q < 10; ++q) {
    const int i = i0 + q;
    if (i < NN) { cursor[i] = excl; start[i] = excl; }
    excl += v[q];
  }
}

__global__ __launch_bounds__(256)
void sgnn_scatter(const int* __restrict__ eidx, int* __restrict__ cursor,
                  int* __restrict__ sorted) {
  const int e = blockIdx.x * 256 + threadIdx.x;
  if (e < NE) {
    const int p = atomicAdd(cursor + eidx[e], 1);
    sorted[p] = e;
  }
}

// ---- weight convert + fused histogram (verified R11) ----
__global__ __launch_bounds__(256)
void sgnn_wconv(const float* __restrict__ nW1, const float* __restrict__ nW2,
                const float* __restrict__ nW3, const float* __restrict__ sW1,
                const float* __restrict__ sW2, const float* __restrict__ sW3,
                const float* __restrict__ Wemb1, const float* __restrict__ Wemb2,
                const int* __restrict__ eidx, int* __restrict__ deg,
                ushort* __restrict__ wout, ushort* __restrict__ tab) {
  const int gid = blockIdx.x * 256 + threadIdx.x;
  if (gid < NE) atomicAdd(deg + eidx[gid], 1);
  if (gid >= 61 * 4096) {
    const int k = gid - 61 * 4096;
    if (k < NTRI) {
      int a, b; tri_ab(k, a, b);
      tab[k] = (ushort)(a | (b << 8) | ((a != b) ? 0x8000 : 0));
    }
    return;
  }
  const int tile = gid >> 12, idx = gid & 4095;
  const int c = idx >> 6, k = idx & 63;
  float v = 0.f;
  if (tile < 12) {
    const int T = tile;
    if (T < 8 || (T == 8 && k < 16)) {
      const int ktri = T * 64 + k;
      if (ktri < NTRI) {
        int a, b; tri_ab(ktri, a, b);
        v = nW1[(a * 32 + b) * 64 + c];
        if (a != b) v += nW1[(b * 32 + a) * 64 + c];
      }
    } else if (T == 8) { if (k < 20) v = nW1[(1216 + (k - 16)) * 64 + c]; }
    else if (T == 9)   v = nW1[(1024 + k) * 64 + c];
    else if (T == 10)  v = nW1[(1088 + k) * 64 + c];
    else               v = nW1[(1152 + k) * 64 + c];
  } else if (tile == 12) v = nW2[k * 64 + c];
  else if (tile < 30)    v = nW3[k * 1088 + (tile - 13) * 64 + c];
  else if (tile < 41) {
    const int T = tile - 30;
    if (T < 8 || (T == 8 && k < 16)) {
      const int ktri = T * 64 + k;
      if (ktri < NTRI) {
        int a, b; tri_ab(ktri, a, b);
        v = sW1[(a * 32 + b) * 64 + c];
        if (a != b) v += sW1[(b * 32 + a) * 64 + c];
      }
    } else if (T == 9) v = sW1[(1024 + k) * 64 + c];
    else if (T == 10)  v = sW1[(1088 + k) * 64 + c];
  } else if (tile == 41) v = sW2[k * 64 + c];
  else if (tile < 59)    v = sW3[k * 1088 + (tile - 42) * 64 + c];
  else if (tile == 59) {
    const int col = idx / 96, kk = idx % 96;
    v = (col < 32 && kk < 65) ? Wemb1[kk * 32 + col] : 0.f;
  } else {
    const int col = idx >> 6;
    v = (col < 32) ? Wemb2[k * 32 + col] : 0.f;
  }
  wout[gid] = f2bf(v);
}

#define WPRE_LOAD(srcbase) do { const ushort* _s = (srcbase);                    \
  wpre0 = *(const short8v*)&_s[(t >> 3) * 64 + (t & 7) * 8];                     \
  wpre1 = *(const short8v*)&_s[(32 + (t >> 3)) * 64 + (t & 7) * 8]; } while (0)

#define WPRE_STORE_TO(Wd) do { ushort* _d = (Wd);                                \
  *(short8v*)&_d[(t >> 3) * STX + (t & 7) * 8] = wpre0;                          \
  *(short8v*)&_d[(32 + (t >> 3)) * STX + (t & 7) * 8] = wpre1; } while (0)

// MFMA with register A-fragments, parametrized W buffer
#define MFMA_K64_RA_B(Wb) do { const ushort* _wl = (Wb);                         \
  acc[0] = __builtin_amdgcn_mfma_f32_16x16x32_bf16(af0.v8,                       \
      *(const bf16x8*)&_wl[(     ll) * STX + lh * 8], acc[0], 0, 0, 0);          \
  acc[1] = __builtin_amdgcn_mfma_f32_16x16x32_bf16(af0.v8,                       \
      *(const bf16x8*)&_wl[(16 + ll) * STX + lh * 8], acc[1], 0, 0, 0);          \
  acc[2] = __builtin_amdgcn_mfma_f32_16x16x32_bf16(af0.v8,                       \
      *(const bf16x8*)&_wl[(32 + ll) * STX + lh * 8], acc[2], 0, 0, 0);          \
  acc[3] = __builtin_amdgcn_mfma_f32_16x16x32_bf16(af0.v8,                       \
      *(const bf16x8*)&_wl[(48 + ll) * STX + lh * 8], acc[3], 0, 0, 0);          \
  acc[0] = __builtin_amdgcn_mfma_f32_16x16x32_bf16(af1.v8,                       \
      *(const bf16x8*)&_wl[(     ll) * STX + 32 + lh * 8], acc[0], 0, 0, 0);     \
  acc[1] = __builtin_amdgcn_mfma_f32_16x16x32_bf16(af1.v8,                       \
      *(const bf16x8*)&_wl[(16 + ll) * STX + 32 + lh * 8], acc[1], 0, 0, 0);     \
  acc[2] = __builtin_amdgcn_mfma_f32_16x16x32_bf16(af1.v8,                       \
      *(const bf16x8*)&_wl[(32 + ll) * STX + 32 + lh * 8], acc[2], 0, 0, 0);     \
  acc[3] = __builtin_amdgcn_mfma_f32_16x16x32_bf16(af1.v8,                       \
      *(const bf16x8*)&_wl[(48 + ll) * STX + 32 + lh * 8], acc[3], 0, 0, 0);     \
} while (0)

// MFMA reading X from LDS, parametrized W buffer
#define MFMA_K64_B(Xb, Wb) do { const ushort* _x = (Xb); const ushort* _wl = (Wb);\
  _Pragma("unroll") for (int kb = 0; kb < 2; ++kb) {                             \
    const bf16x8 af_ = *(const bf16x8*)&_x[(w * 16 + ll) * STX + kb * 32 + lh * 8]; \
    acc[0] = __builtin_amdgcn_mfma_f32_16x16x32_bf16(af_,                        \
        *(const bf16x8*)&_wl[(     ll) * STX + kb * 32 + lh * 8], acc[0], 0, 0, 0); \
    acc[1] = __builtin_amdgcn_mfma_f32_16x16x32_bf16(af_,                        \
        *(const bf16x8*)&_wl[(16 + ll) * STX + kb * 32 + lh * 8], acc[1], 0, 0, 0); \
    acc[2] = __builtin_amdgcn_mfma_f32_16x16x32_bf16(af_,                        \
        *(const bf16x8*)&_wl[(32 + ll) * STX + kb * 32 + lh * 8], acc[2], 0, 0, 0); \
    acc[3] = __builtin_amdgcn_mfma_f32_16x16x32_bf16(af_,                        \
        *(const bf16x8*)&_wl[(48 + ll) * STX + kb * 32 + lh * 8], acc[3], 0, 0, 0); \
  } } while (0)

#define ZERO_ACC() do { _Pragma("unroll") for (int q = 0; q < 4; ++q)            \
    acc[q] = (f32x4){0.f, 0.f, 0.f, 0.f}; } while (0)

#define PACK_STORE16(dstp) do {                                                  \
  unsigned pk[8];                                                                \
  _Pragma("unroll") for (int q = 0; q < 8; ++q)                                  \
    pk[q] = (unsigned)f2bf(xv[2 * q]) | ((unsigned)f2bf(xv[2 * q + 1]) << 16);   \
  *(uint4v*)(dstp)       = (uint4v){pk[0], pk[1], pk[2], pk[3]};                 \
  *(uint4v*)((dstp) + 8) = (uint4v){pk[4], pk[5], pk[6], pk[7]};                 \
} while (0)

#define PACK_AF() do {                                                           \
  _Pragma("unroll") for (int q2 = 0; q2 < 4; ++q2) {                             \
    af0.u[q2] = (unsigned)f2bf(xv[2 * q2]) | ((unsigned)f2bf(xv[2 * q2 + 1]) << 16); \
    af1.u[q2] = (unsigned)f2bf(xv[8 + 2 * q2]) | ((unsigned)f2bf(xv[8 + 2 * q2 + 1]) << 16); \
  } } while (0)

#define TRI8(kt, off) do {                                                       \
  int prev_a = -1; float fa0 = 0.f, fa1 = 0.f, fa2 = 0.f;                        \
  _Pragma("unroll") for (int q = 0; q < 8; ++q) {                                \
    const int tb = tabL[(kt) + q];                                               \
    const int a_ = tb & 31, b_ = (tb >> 8) & 31;                                 \
    if (a_ != prev_a) { fa0 = bfu(frA[a_]); fa1 = bfu(frA[32 + a_]);             \
                        fa2 = bfu(frA[64 + a_]); prev_a = a_; }                  \
    const float v = fmaf(fa0, bfu(frA[b_]),                                      \
        fmaf(fa1, bfu(frA[32 + b_]), fa2 * bfu(frA[64 + b_])));                  \
    const float wsel = (tb & 0x8000) ? 2.f : 1.f;                                \
    sumsq = fmaf(v * wsel, v, sumsq);                                            \
    xv[(off) + q] = v;                                                           \
  } } while (0)

#define XV8_LOAD(p, off) do { const float* _p = (p);                             \
  const float4 va = *(const float4*)(_p);                                        \
  const float4 vb = *(const float4*)(_p + 4);                                    \
  xv[(off)+0]=va.x; xv[(off)+1]=va.y; xv[(off)+2]=va.z; xv[(off)+3]=va.w;        \
  xv[(off)+4]=vb.x; xv[(off)+5]=vb.y; xv[(off)+6]=vb.z; xv[(off)+7]=vb.w;        \
} while (0)

#define XV_LOAD16(p) do { const float* _p = (p);                                 \
  _Pragma("unroll") for (int q = 0; q < 4; ++q) {                                \
    const float4 v4 = *(const float4*)(_p + 4 * q);                              \
    xv[4 * q + 0] = v4.x; xv[4 * q + 1] = v4.y;                                  \
    xv[4 * q + 2] = v4.z; xv[4 * q + 3] = v4.w; } } while (0)

#define CONSUME_NT() do {                                                        \
  _Pragma("unroll") for (int r = 0; r < 4; ++r) {                                \
    const int row_ = w * 16 + lh * 4 + r;                                        \
    const unsigned u0 = *(const unsigned*)&smFh[row_ * SFH +      nt * 2];       \
    const unsigned u1 = *(const unsigned*)&smFh[row_ * SFH + 32 + nt * 2];       \
    const unsigned u2 = *(const unsigned*)&smFh[row_ * SFH + 64 + nt * 2];       \
    union { unsigned x; float f; } l0, h0, l1, h1, l2, h2;                       \
    l0.x = u0 << 16; h0.x = u0 & 0xffff0000u;                                    \
    l1.x = u1 << 16; h1.x = u1 & 0xffff0000u;                                    \
    l2.x = u2 << 16; h2.x = u2 & 0xffff0000u;                                    \
    _Pragma("unroll") for (int nc = 0; nc < 4; ++nc) {                           \
      const float cv = (acc[nc][r] + b3v[nc]) * ifnr[r];                         \
      const int p = nc & 1;                                                      \
      const float f0 = (nc < 2) ? l0.f : h0.f;                                   \
      const float f1 = (nc < 2) ? l1.f : h1.f;                                   \
      const float f2 = (nc < 2) ? l2.f : h2.f;                                   \
      fch[(r * 3 + 0) * 2 + p] = fmaf(f0, cv, fch[(r * 3 + 0) * 2 + p]);         \
      fch[(r * 3 + 1) * 2 + p] = fmaf(f1, cv, fch[(r * 3 + 1) * 2 + p]);         \
      fch[(r * 3 + 2) * 2 + p] = fmaf(f2, cv, fch[(r * 3 + 2) * 2 + p]);         \
    }                                                                            \
  } } while (0)

#define STAGE_FS() do {                                                          \
  _Pragma("unroll") for (int r = 0; r < 4; ++r) {                                \
    const int row_ = w * 16 + lh * 4 + r;                                        \
    _Pragma("unroll") for (int i = 0; i < 3; ++i) {                              \
      F[row_ * SFB + i * 32 + ll]      = f2bf(fch[(r * 3 + i) * 2 + 0]);         \
      F[row_ * SFB + i * 32 + ll + 16] = f2bf(fch[(r * 3 + i) * 2 + 1]);         \
    }                                                                            \
    _Pragma("unroll") for (int nc = 0; nc < 4; ++nc)                             \
      S[row_ * SSB + nc * 16 + ll] = f2bf(cs[nc * 4 + r]);                       \
  } } while (0)

// LDS carve (43872 B): R13 layout + Wl1 tail region for GEMM3 W-dbuf
#define LDS_BYTES 43872

__global__ __launch_bounds__(256, 3)
void sgnn_edge(const float* __restrict__ f, const float* __restrict__ s,
               const float* __restrict__ edge_f, const float* __restrict__ edge_s,
               const float* __restrict__ b1, const float* __restrict__ b2,
               const float* __restrict__ b3,
               const ushort* __restrict__ wbf, const ushort* __restrict__ tab_g,
               const int* __restrict__ eidx, const int* __restrict__ sorted,
               const int* __restrict__ start_g, const int* __restrict__ deg_g,
               float* __restrict__ fc_sum, float* __restrict__ sc_sum) {
  __shared__ __align__(16) char sbuf[LDS_BYTES];
  ushort* smFh = (ushort*)sbuf;            // [64][SFH]
  ushort* F    = (ushort*)sbuf;            // flush overlay
  ushort* Xl   = (ushort*)(sbuf + 13056);  // h1/h2; W-dbuf alt during GEMM1
  ushort* S    = (ushort*)(sbuf + 13056);  // flush overlay
  ushort* Aemb = (ushort*)(sbuf + 13056);  // embed A [96][SAE]
  ushort* Wl   = (ushort*)(sbuf + 22272);
  int*    snode = (int*)(sbuf + 31488);
  int*    srow0 = snode + 8;
  int*    srow1 = snode + 16;
  int*    sst   = snode + 24;
  int*    sdg   = snode + 32;
  ushort* tabL = (ushort*)(sbuf + 33088);
  float*  iFn  = (float*)(sbuf + 33088);
  int*    es_s = (int*)(sbuf + 34144);
  ushort* e0s  = (ushort*)(sbuf + 34400);
  ushort* e1s  = (ushort*)(sbuf + 34528);
  ushort* Wl1  = (ushort*)(sbuf + 34656);  // GEMM3 W double-buffer

  const int t = threadIdx.x, j = t & 63, w = t >> 6, eb = w * 16;
  const int lh = j >> 4, ll = j & 15;
  const int bid = blockIdx.x;
  const ushort* wembT = wbf + 59 * 4096;
  short8v wpre0, wpre1;

  if (t < 64) {
    const int e = sorted[bid * 64 + t];
    es_s[t] = e;
    e0s[t] = (ushort)eidx[e];
    e1s[t] = (ushort)eidx[NE + e];
  }
  for (int idx = t; idx < NTRI; idx += 256) tabL[idx] = tab_g[idx];
  __syncthreads();

  int str = 0, dgr = 0;
  if (j < 16) {
    const int n_ = e0s[eb + j];
    str = start_g[n_];
    dgr = deg_g[n_];
  }
  WPRE_LOAD(wbf + 0);                // W1 tile 0

  // ---- MFMA embed (verified R9-R16) ----
  #pragma unroll 1
  for (int h = 0; h < 2; ++h) {
    const int hb = h * 32;
    #pragma unroll 1
    for (int cc = t; cc < 576; cc += 256) {
      const int row = cc / 6, seg = cc - row * 6;
      const int lel = (row * 43) >> 7, il = row - lel * 3;
      const int k0 = seg * 16;
      float xv[16];
      if (seg < 4) {
        const int nd = (seg < 2) ? (int)e0s[hb + lel] : (int)e1s[hb + lel];
        XV_LOAD16(f + nd * 96 + il * 32 + (seg & 1) * 16);
      } else if (seg == 4) {
        xv[0] = edge_f[es_s[hb + lel] * 3 + il];
        #pragma unroll
        for (int m = 1; m < 16; ++m) xv[m] = 0.f;
      } else {
        #pragma unroll
        for (int m = 0; m < 16; ++m) xv[m] = 0.f;
      }
      PACK_STORE16(&Aemb[row * SAE + k0]);
    }
    __syncthreads();
    #pragma unroll 1
    for (int job = w * 3; job < w * 3 + 3; ++job) {
      const int mt = job >> 1, nt = job & 1;
      f32x4 ac = (f32x4){0.f, 0.f, 0.f, 0.f};
      #pragma unroll
      for (int kb = 0; kb < 3; ++kb) {
        const bf16x8 av = *(const bf16x8*)&Aemb[(mt * 16 + ll) * SAE + kb * 32 + lh * 8];
        const bf16x8 bv = *(const bf16x8*)&wembT[(nt * 16 + ll) * 96 + kb * 32 + lh * 8];
        ac = __builtin_amdgcn_mfma_f32_16x16x32_bf16(av, bv, ac, 0, 0, 0);
      }
      #pragma unroll
      for (int r = 0; r < 4; ++r) {
        const int rr = mt * 16 + lh * 4 + r;
        const int lel = (rr * 43) >> 7, il = rr - lel * 3;
        smFh[(hb + lel) * SFH + il * 32 + nt * 16 + ll] = f2bf(ac[r]);
      }
    }
    __syncthreads();
  }

  f32x4 acc[4];
  ZERO_ACC();
  float sumsq = 0.f;
  const int rowA = w * 16 + ll;
  const ushort* frA = smFh + rowA * SFH;

  // ---- GEMM1: 12 stages, W double-buffered in {Wl, Xl}, ONE barrier/stage ----
  WPRE_STORE_TO(Wl);                 // W0 -> buf0 (embed done with Wl region)
  WPRE_LOAD(wbf + 1 * 4096);         // W1
  __syncthreads();
  #pragma unroll 1
  for (int T = 0; T < 12; ++T) {
    ushort* Wc = (T & 1) ? Xl : Wl;
    ushort* Wn = (T & 1) ? Wl : Xl;
    float xv[16];
    union { unsigned u[4]; bf16x8 v8; } af0, af1;
    if (T < 8) {
      TRI8(T * 64 + lh * 8, 0);
      TRI8(T * 64 + 32 + lh * 8, 8);
    } else if (T == 8) {
      #pragma unroll
      for (int kb2 = 0; kb2 < 2; ++kb2)
        #pragma unroll
        for (int q = 0; q < 8; ++q) {
          const int k = kb2 * 32 + lh * 8 + q;
          float v = 0.f;
          if (k < 16) {
            const int tb = tabL[512 + k];
            const int a_ = tb & 31, b_ = (tb >> 8) & 31;
            v = fmaf(bfu(frA[a_]), bfu(frA[b_]),
                fmaf(bfu(frA[32 + a_]), bfu(frA[32 + b_]),
                     bfu(frA[64 + a_]) * bfu(frA[64 + b_])));
            const float wsel = (tb & 0x8000) ? 2.f : 1.f;
            sumsq = fmaf(v * wsel, v, sumsq);
          } else if (k < 20) {
            v = edge_s[es_s[rowA] * 68 + 64 + (k - 16)];
          }
          xv[kb2 * 8 + q] = v;
        }
    } else {
      const float* p = (T == 9)  ? (s + e0s[rowA] * 64)
                     : (T == 10) ? (s + e1s[rowA] * 64)
                                 : (edge_s + es_s[rowA] * 68);
      XV8_LOAD(p + lh * 8, 0);
      XV8_LOAD(p + 32 + lh * 8, 8);
    }
    PACK_AF();
    WPRE_STORE_TO(Wn);               // W(T+1); T=11 stores W2 -> Wl
    WPRE_LOAD(wbf + (T + 2) * 4096); // T=11 loads tile 13 (W3_0)
    MFMA_K64_RA_B(Wc);
    __syncthreads();
  }

  // ---- sumsq (wave-local) + h1 epilogue; W2 already in Wl ----
  {
    float ss = sumsq;
    ss += __shfl_xor(ss, 16);
    ss += __shfl_xor(ss, 32);
    if (j < 16) iFn[eb + j] = 1.f / (sqrtf(ss) + 1.f);  // own wave's rows
  }
  #pragma unroll
  for (int nc = 0; nc < 4; ++nc) {
    const float bv = b1[nc * 16 + ll];
    #pragma unroll
    for (int r = 0; r < 4; ++r)
      Xl[(w * 16 + lh * 4 + r) * STX + nc * 16 + ll] = f2bf(fmaxf(acc[nc][r] + bv, 0.f));
  }
  ZERO_ACC();
  MFMA_K64_B(Xl, Wl);                // GEMM2 (A rows wave-private, W2 barrier'd)
  #pragma unroll
  for (int nc = 0; nc < 4; ++nc) {
    const float bv = b2[nc * 16 + ll];
    #pragma unroll
    for (int r = 0; r < 4; ++r)
      Xl[(w * 16 + lh * 4 + r) * STX + nc * 16 + ll] = f2bf(fmaxf(acc[nc][r] + bv, 0.f));
  }
  WPRE_STORE_TO(Wl1);                // W3 tile 13
  WPRE_LOAD(wbf + 14 * 4096);        // tile 14
  __syncthreads();                   // covers: GEMM2 done (Wl reusable), tile13 visible

  // ---- GEMM3: 17 tiles, W double-buffered {Wl1, Wl}, ONE barrier/tile ----
  float fch[24];
  #pragma unroll
  for (int q = 0; q < 24; ++q) fch[q] = 0.f;
  float cs[16];
  float ifnr[4];
  #pragma unroll
  for (int r = 0; r < 4; ++r) ifnr[r] = iFn[w * 16 + lh * 4 + r];  // own wave's rows

  #pragma unroll 1
  for (int nt = 0; nt < 17; ++nt) {
    ushort* Wc = (nt & 1) ? Wl : Wl1;      // nt=0 -> Wl1 (tile 13)
    ushort* Wn = (nt & 1) ? Wl1 : Wl;
    if (nt < 16) {
      WPRE_STORE_TO(Wn);             // tile 14+nt
      if (nt < 15) WPRE_LOAD(wbf + (15 + nt) * 4096);
    }
    float b3v[4];
    #pragma unroll
    for (int nc = 0; nc < 4; ++nc) b3v[nc] = b3[nt * 64 + nc * 16 + ll];
    ZERO_ACC();
    MFMA_K64_B(Xl, Wc);
    if (nt < 16) {
      CONSUME_NT();
    } else {
      #pragma unroll
      for (int nc = 0; nc < 4; ++nc)
        #pragma unroll
        for (int r = 0; r < 4; ++r)
          cs[nc * 4 + r] = (acc[nc][r] + b3v[nc]) * ifnr[r];
    }
    __syncthreads();
  }

  // ---- stage F/S (bf16), then run-flush (verified R5/R10/R11) ----
  STAGE_FS();
  if (t < 8) snode[t] = -1;
  __syncthreads();

  {
    float r0 = 0.f, r1 = 0.f, rs = 0.f;
    int runlen = 0;
    const int gwb = bid * 64 + eb;
    #pragma unroll 1
    for (int m = 0; m < 16; ++m) {
      const int row = eb + m;
      r0 += bfu(F[row * SFB + j]);
      if (j < 32) r1 += bfu(F[row * SFB + 64 + j]);
      rs += bfu(S[row * SSB + j]);
      ++runlen;
      const int n = e0s[row];
      if (m == 15 || e0s[row + 1] != n) {
        const int st = __shfl(str, m);
        const int dg = __shfl(dgr, m);
        const int g1v = gwb + m, g0v = g1v - runlen + 1;
        if (g0v == st && runlen == dg) {
          fc_sum[n * 96 + j] = r0;
          if (j < 32) fc_sum[n * 96 + 64 + j] = r1;
          sc_sum[n * 64 + j] = rs;
        } else {
          const int slot = (g0v == gwb) ? 2 * w : 2 * w + 1;
          if (j == 0) {
            snode[slot] = n; srow0[slot] = row - runlen + 1; srow1[slot] = row;
            sst[slot] = st; sdg[slot] = dg;
          }
        }
        r0 = r1 = rs = 0.f; runlen = 0;
      }
    }
  }
  __syncthreads();

  if (t < 160) {
    const int ch = t;
    int prevn = -1;
    #pragma unroll 1
    for (int ss = 0; ss < 8; ++ss) {
      const int n = snode[ss];
      if (n < 0) continue;
      if (n != prevn) {
        float v = 0.f;
        #pragma unroll 1
        for (int k2 = ss; k2 < 8; ++k2) {
          if (snode[k2] == n) {
            #pragma unroll 1
            for (int row = srow0[k2]; row <= srow1[k2]; ++row)
              v += (ch < 96) ? bfu(F[row * SFB + ch]) : bfu(S[row * SSB + (ch - 96)]);
          } else if (k2 > ss && snode[k2] >= 0) break;
        }
        const bool cib = (sst[ss] >= bid * 64) && (sst[ss] + sdg[ss] <= bid * 64 + 64);
        float* dst = (ch < 96) ? (fc_sum + n * 96 + ch) : (sc_sum + n * 64 + (ch - 96));
        if (cib) *dst = v; else atomicAdd(dst, v);
      }
      prevn = n;
    }
  }
}

__global__ __launch_bounds__(256, 3)
void sgnn_node(const float* __restrict__ f, const float* __restrict__ s,
               const float* __restrict__ b1, const float* __restrict__ b2,
               const float* __restrict__ b3,
               const ushort* __restrict__ wbf, const ushort* __restrict__ tab_g,
               const float* __restrict__ fcm, const float* __restrict__ scm,
               const int* __restrict__ deg_g,
               float* __restrict__ of, float* __restrict__ os) {
  __shared__ __align__(16) char sbuf[LDS_BYTES];
  ushort* smFh = (ushort*)sbuf;
  ushort* F    = (ushort*)sbuf;
  ushort* Xl   = (ushort*)(sbuf + 13056);
  ushort* S    = (ushort*)(sbuf + 13056);
  ushort* Aemb = (ushort*)(sbuf + 13056);
  ushort* Wl   = (ushort*)(sbuf + 22272);
  float*  icntL = (float*)(sbuf + 31488);
  ushort* tabL = (ushort*)(sbuf + 33088);
  float*  iFn  = (float*)(sbuf + 33088);
  ushort* Wl1  = (ushort*)(sbuf + 34656);

  const int t = threadIdx.x, j = t & 63, w = t >> 6, eb = w * 16;
  const int lh = j >> 4, ll = j & 15;
  const int nbase = blockIdx.x * 64;
  const ushort* wembTn = wbf + 60 * 4096;
  short8v wpre0, wpre1;

  for (int idx = t; idx < NTRI; idx += 256) tabL[idx] = tab_g[idx];
  if (t < 64)
    icntL[t] = 1.f / fmaxf((float)deg_g[min(nbase + t, NN - 1)], 1.f);
  WPRE_LOAD(wbf + 30 * 4096);
  __syncthreads();

  // ---- MFMA embed ----
  #pragma unroll 1
  for (int h = 0; h < 2; ++h) {
    const int hb = h * 32;
    #pragma unroll 1
    for (int cc = t; cc < 384; cc += 256) {
      const int row = cc >> 2, seg = cc & 3;
      const int lel = (row * 43) >> 7, il = row - lel * 3;
      const int nc = min(nbase + hb + lel, NN - 1);
      const int k0 = seg * 16;
      float xv[16];
      if (seg < 2) {
        XV_LOAD16(f + nc * 96 + il * 32 + seg * 16);
      } else {
        XV_LOAD16(fcm + nc * 96 + il * 32 + (seg - 2) * 16);
        const float ic = icntL[hb + lel];
        #pragma unroll
        for (int m = 0; m < 16; ++m) xv[m] *= ic;
      }
      PACK_STORE16(&Aemb[row * SAN + k0]);
    }
    __syncthreads();
    #pragma unroll 1
    for (int job = w * 3; job < w * 3 + 3; ++job) {
      const int mt = job >> 1, nt = job & 1;
      f32x4 ac = (f32x4){0.f, 0.f, 0.f, 0.f};
      #pragma unroll
      for (int kb = 0; kb < 2; ++kb) {
        const bf16x8 av = *(const bf16x8*)&Aemb[(mt * 16 + ll) * SAN + kb * 32 + lh * 8];
        const bf16x8 bv = *(const bf16x8*)&wembTn[(nt * 16 + ll) * 64 + kb * 32 + lh * 8];
        ac = __builtin_amdgcn_mfma_f32_16x16x32_bf16(av, bv, ac, 0, 0, 0);
      }
      #pragma unroll
      for (int r = 0; r < 4; ++r) {
        const int rr = mt * 16 + lh * 4 + r;
        const int lel = (rr * 43) >> 7, il = rr - lel * 3;
        smFh[(hb + lel) * SFH + il * 32 + nt * 16 + ll] = f2bf(ac[r]);
      }
    }
    __syncthreads();
  }

  f32x4 acc[4];
  ZERO_ACC();
  float sumsq = 0.f;
  const int rowA = w * 16 + ll;
  const ushort* frA = smFh + rowA * SFH;
  const int ncA = min(nbase + rowA, NN - 1);

  // ---- GEMM1: 11 stages, W dbuf {Xl, Wl} with flipped parity (odd count) ----
  WPRE_STORE_TO(Xl);                 // tile 30 -> Xl
  WPRE_LOAD(wbf + 31 * 4096);
  __syncthreads();
  #pragma unroll 1
  for (int T = 0; T < 11; ++T) {
    ushort* Wc = (T & 1) ? Wl : Xl;  // T=0 -> Xl
    ushort* Wn = (T & 1) ? Xl : Wl;  // T=10 stores tile41 (W2) -> Wl
    float xv[16];
    union { unsigned u[4]; bf16x8 v8; } af0, af1;
    if (T < 8) {
      TRI8(T * 64 + lh * 8, 0);
      TRI8(T * 64 + 32 + lh * 8, 8);
    } else if (T == 8) {
      #pragma unroll
      for (int kb2 = 0; kb2 < 2; ++kb2)
        #pragma unroll
        for (int q = 0; q < 8; ++q) {
          const int k = kb2 * 32 + lh * 8 + q;
          float v = 0.f;
          if (k < 16) {
            const int tb = tabL[512 + k];
            const int a_ = tb & 31, b_ = (tb >> 8) & 31;
            v = fmaf(bfu(frA[a_]), bfu(frA[b_]),
                fmaf(bfu(frA[32 + a_]), bfu(frA[32 + b_]),
                     bfu(frA[64 + a_]) * bfu(frA[64 + b_])));
            const float wsel = (tb & 0x8000) ? 2.f : 1.f;
            sumsq = fmaf(v * wsel, v, sumsq);
          }
          xv[kb2 * 8 + q] = v;
        }
    } else if (T == 9) {
      XV8_LOAD(s + ncA * 64 + lh * 8, 0);
      XV8_LOAD(s + ncA * 64 + 32 + lh * 8, 8);
    } else {
      const float ic = icntL[rowA];
      XV8_LOAD(scm + ncA * 64 + lh * 8, 0);
      XV8_LOAD(scm + ncA * 64 + 32 + lh * 8, 8);
      #pragma unroll
      for (int m = 0; m < 16; ++m) xv[m] *= ic;
    }
    PACK_AF();
    WPRE_STORE_TO(Wn);               // tile 31+T
    WPRE_LOAD(wbf + (32 + T) * 4096); // T=10 loads tile 42 (W3_0)
    MFMA_K64_RA_B(Wc);
    __syncthreads();
  }

  {
    float ss = sumsq;
    ss += __shfl_xor(ss, 16);
    ss += __shfl_xor(ss, 32);
    if (j < 16) iFn[eb + j] = 1.f / (sqrtf(ss) + 1.f);
  }
  #pragma unroll
  for (int nc = 0; nc < 4; ++nc) {
    const float bv = b1[nc * 16 + ll];
    #pragma unroll
    for (int r = 0; r < 4; ++r)
      Xl[(w * 16 + lh * 4 + r) * STX + nc * 16 + ll] = f2bf(fmaxf(acc[nc][r] + bv, 0.f));
  }
  ZERO_ACC();
  MFMA_K64_B(Xl, Wl);                // GEMM2 (W2 in Wl)
  #pragma unroll
  for (int nc = 0; nc < 4; ++nc) {
    const float bv = b2[nc * 16 + ll];
    #pragma unroll
    for (int r = 0; r < 4; ++r)
      Xl[(w * 16 + lh * 4 + r) * STX + nc * 16 + ll] = f2bf(fmaxf(acc[nc][r] + bv, 0.f));
  }
  WPRE_STORE_TO(Wl1);                // W3 tile 42
  WPRE_LOAD(wbf + 43 * 4096);
  __syncthreads();

  // ---- GEMM3 ----
  float fch[24];
  #pragma unroll
  for (int q = 0; q < 24; ++q) fch[q] = 0.f;
  float cs[16];
  float ifnr[4];
  #pragma unroll
  for (int r = 0; r < 4; ++r) ifnr[r] = iFn[w * 16 + lh * 4 + r];

  #pragma unroll 1
  for (int nt = 0; nt < 17; ++nt) {
    ushort* Wc = (nt & 1) ? Wl : Wl1;    // nt=0 -> Wl1 (tile 42)
    ushort* Wn = (nt & 1) ? Wl1 : Wl;
    if (nt < 16) {
      WPRE_STORE_TO(Wn);             // tile 43+nt
      if (nt < 15) WPRE_LOAD(wbf + (44 + nt) * 4096);
    }
    float b3v[4];
    #pragma unroll
    for (int nc = 0; nc < 4; ++nc) b3v[nc] = b3[nt * 64 + nc * 16 + ll];
    ZERO_ACC();
    MFMA_K64_B(Xl, Wc);
    if (nt < 16) {
      CONSUME_NT();
    } else {
      #pragma unroll
      for (int nc = 0; nc < 4; ++nc)
        #pragma unroll
        for (int r = 0; r < 4; ++r)
          cs[nc * 4 + r] = (acc[nc][r] + b3v[nc]) * ifnr[r];
    }
    __syncthreads();
  }

  // ---- stage F/S + residual writes ----
  STAGE_FS();
  __syncthreads();

  #pragma unroll 1
  for (int m = 0; m < 16; ++m) {
    const int row = eb + m;
    const int n_m = nbase + row;
    if (n_m < NN) {
      of[n_m * 96 + j] = bfu(F[row * SFB + j]) + f[n_m * 96 + j];
      if (j < 32)
        of[n_m * 96 + 64 + j] = bfu(F[row * SFB + 64 + j]) + f[n_m * 96 + 64 + j];
      os[n_m * 64 + j] = bfu(S[row * SSB + j]) + s[n_m * 64 + j];
    }
  }
}

extern "C" void kernel_launch(void* const* d_in, const int* in_sizes, int n_in,
                              void* d_out, int out_size, void* d_ws, size_t ws_size,
                              hipStream_t stream) {
  const float* f      = (const float*)d_in[0];
  const float* s      = (const float*)d_in[1];
  const float* edge_f = (const float*)d_in[2];
  const float* edge_s = (const float*)d_in[3];
  const float* Wemb1  = (const float*)d_in[4];
  const float* nW1 = (const float*)d_in[5];
  const float* nb1 = (const float*)d_in[6];
  const float* nW2 = (const float*)d_in[7];
  const float* nb2 = (const float*)d_in[8];
  const float* nW3 = (const float*)d_in[9];
  const float* nb3 = (const float*)d_in[10];
  const float* Wemb2 = (const float*)d_in[11];
  const float* sW1 = (const float*)d_in[12];
  const float* sb1 = (const float*)d_in[13];
  const float* sW2 = (const float*)d_in[14];
  const float* sb2 = (const float*)d_in[15];
  const float* sW3 = (const float*)d_in[16];
  const float* sb3 = (const float*)d_in[17];
  const int* eidx  = (const int*)d_in[18];

  float* of = (float*)d_out;
  float* os = of + (size_t)NN * 96;

  int* deg    = (int*)d_ws;
  int* cursor = deg + NN;
  int* start  = cursor + NN;
  int* sorted = start + NN;
  ushort* wbf = (ushort*)(sorted + NE);
  ushort* tab = wbf + 61 * 4096;

  hipMemsetAsync(deg, 0, (size_t)NN * 4, stream);
  hipMemsetAsync(d_out, 0, (size_t)NN * 160 * 4, stream);

  hipLaunchKernelGGL(sgnn_wconv, dim3((61 * 4096 + NTRI + 255) / 256), dim3(256),
                     0, stream, nW1, nW2, nW3, sW1, sW2, sW3, Wemb1, Wemb2,
                     eidx, deg, wbf, tab);
  hipLaunchKernelGGL(sgnn_scan, dim3(1), dim3(1024), 0, stream, deg, cursor, start);
  hipLaunchKernelGGL(sgnn_scatter, dim3((NE + 255) / 256), dim3(256), 0, stream,
                     eidx, cursor, sorted);
  hipLaunchKernelGGL(sgnn_edge, dim3(NE / 64), dim3(256), 0, stream,
                     f, s, edge_f, edge_s, nb1, nb2, nb3,
                     wbf, tab, eidx, sorted, start, deg,
                     of /*fc_sum*/, os /*sc_sum*/);
  hipLaunchKernelGGL(sgnn_node, dim3((NN + 63) / 64), dim3(256), 0, stream,
                     f, s, sb1, sb2, sb3,
                     wbf, tab, of /*fc sums*/, os /*sc sums*/, deg, of, os);
}